// Round 11
// baseline (323.104 us; speedup 1.0000x reference)
//
#include <hip/hip_runtime.h>

// ---------------------------------------------------------------------------
// Algebraic collapse: the scan is linear & batch-independent.
//   m_{t+1} = A m_t + beta,  A[(j,e),(i,d)] = gate[i,j]*W[i,j,e,d]
//   out = inp @ Weff^T + beff,  Weff = Wpost * S * Wpre,
//   S = (A^10)[block15, block0],  c = (sum_{k<10} A^k beta)[block15]
// Round 13 (254us verified base: A^5*A^5 dual chains). Two shavings:
//   * build_AT fused into build_all: per 32x32 tile read W once, write A
//     row-major AND AT via LDS transpose (same arithmetic -> bit-identical;
//     kills 1 dispatch + 33.6MB A re-read).
//   * final_gemm: single-barrier double-buffer (issue next tile's global
//     loads -> compute MFMA -> write regs to alt LDS buffer -> 1 barrier).
//     32 barriers -> 17, load latency hidden under MFMA. LDS 61KB.
// Dispatches: 15 -> 14.
// ---------------------------------------------------------------------------

typedef __bf16 bf16x8 __attribute__((ext_vector_type(8)));
typedef float f32x4 __attribute__((ext_vector_type(4)));
typedef __attribute__((address_space(3))) unsigned int lds_u32;
typedef const __attribute__((address_space(1))) unsigned int glb_u32;

__device__ __forceinline__ unsigned short f2bf(float x) {
  unsigned int u = __float_as_uint(x);
  u += 0x7FFFu + ((u >> 16) & 1u);   // round-to-nearest-even
  return (unsigned short)(u >> 16);
}
__device__ __forceinline__ float bf2f(unsigned short s) {
  return __uint_as_float(((unsigned int)s) << 16);
}
__device__ __forceinline__ bf16x8 ldg8(const unsigned short* p) {
  return __builtin_bit_cast(bf16x8, *(const uint4*)p);
}
__device__ __forceinline__ f32x4 mfma16(bf16x8 a, bf16x8 b, f32x4 c) {
  return __builtin_amdgcn_mfma_f32_16x16x32_bf16(a, b, c, 0, 0, 0);
}

#define ND 2048   // num*dim
#define MT 144    // padded iterate rows (129 used: 128 propagator + 1 bias)
#define KS 8      // split-K chunks (256 k each)
#define CKS 16    // contraction split-K chunks (128 k each)

// ---------------------------------------------------------------------------
// Phase 0 (fused): tiled A+AT build (LDS transpose, W read once), Q-chain
// init Q1 (+beta), R-chain init R1, split inp. 1024 blocks; the tile job
// runs exactly 4 uniform iterations/block (4096 tiles) so barriers are safe.
// ---------------------------------------------------------------------------
__global__ __launch_bounds__(256) void build_all(
    const float* __restrict__ W, const float* __restrict__ life,
    const float* __restrict__ bl, const float* __restrict__ inp,
    unsigned short* __restrict__ Ahi, unsigned short* __restrict__ Alo,
    unsigned short* __restrict__ AThi, unsigned short* __restrict__ ATlo,
    unsigned short* __restrict__ Qhi, unsigned short* __restrict__ Qlo,
    unsigned short* __restrict__ Rhi, unsigned short* __restrict__ Rlo,
    float* __restrict__ beta,
    unsigned short* __restrict__ Ihi, unsigned short* __restrict__ Ilo) {
  __shared__ unsigned short Th[32][36], Tl[32][36];
  const int tid = blockIdx.x * 256 + threadIdx.x;
  const int NT = gridDim.x * 256;
  const int t = threadIdx.x;

  // Job A: per 32x32 tile of A: read W, scale+split, write A and AT.
  // tile tt -> n-tile nt = tt&63, k-tile kt = tt>>6.
  {
    const int r = t >> 3;              // 0..31 row within tile
    const int c4 = (t & 7) * 4;        // 0,4,...,28
    for (int tt = blockIdx.x; tt < 4096; tt += gridDim.x) {
      int nt = tt & 63, kt = tt >> 6;
      int j = nt >> 2, e0 = (nt & 3) * 32;
      int i = kt >> 2, d0 = (kt & 3) * 32;
      float gval = life[i * 16 + j];
      float gate = gval > 0.f ? gval : 0.f;
      const float* src = W + ((size_t)(i * 16 + j) * 16384 + (e0 + r) * 128 + d0 + c4);
      float4 v = *(const float4*)src;
      float vals[4] = {v.x, v.y, v.z, v.w};
      union { unsigned short u[4]; uint2 d2; } oh, ol;
#pragma unroll
      for (int x = 0; x < 4; ++x) {
        float s = gate * vals[x];
        oh.u[x] = f2bf(s);
        ol.u[x] = f2bf(s - bf2f(oh.u[x]));
      }
      size_t aidx = (size_t)(j * 128 + e0 + r) * ND + i * 128 + d0 + c4;
      *(uint2*)(Ahi + aidx) = oh.d2;
      *(uint2*)(Alo + aidx) = ol.d2;
      __syncthreads();                 // protect prior iteration's LDS reads
#pragma unroll
      for (int x = 0; x < 4; ++x) { Th[r][c4 + x] = oh.u[x]; Tl[r][c4 + x] = ol.u[x]; }
      __syncthreads();
      union { unsigned short u[4]; uint2 d2; } th, tl;
#pragma unroll
      for (int x = 0; x < 4; ++x) { th.u[x] = Th[c4 + x][r]; tl.u[x] = Tl[c4 + x][r]; }
      size_t tidx = (size_t)(i * 128 + d0 + r) * ND + j * 128 + e0 + c4;
      *(uint2*)(AThi + tidx) = th.d2;
      *(uint2*)(ATlo + tidx) = tl.d2;
    }
  }

  // Job B: Q1[c=d][n=(j,e)] = gate[0,j]*W[0,j,e,d]; row 128 = beta; rest 0.
  for (int item = tid; item < MT * ND; item += NT) {
    int m = item >> 11, n = item & 2047;
    int j = n >> 7, e = n & 127;
    unsigned short hh = 0, ll = 0;
    if (m < 128) {
      float gval = life[j];                         // i = 0
      float gate = gval > 0.f ? gval : 0.f;
      float v = gate * W[j * 16384 + e * 128 + m];
      hh = f2bf(v); ll = f2bf(v - bf2f(hh));
    } else if (m == 128) {
      float s = 0.f;
#pragma unroll
      for (int i = 0; i < 16; ++i) {
        float gval = life[i * 16 + j];
        float gate = gval > 0.f ? gval : 0.f;
        s += gate * bl[(i * 16 + j) * 128 + e];
      }
      beta[n] = s;
      hh = f2bf(s); ll = f2bf(s - bf2f(hh));
    }
    Qhi[item] = hh;
    Qlo[item] = ll;
  }

  // Job B2: R1[r][n=(i,d)] = A[1920+r][n] = gate[i,15]*W[i,15,r,d]; rows>=128: 0
  for (int item = tid; item < MT * ND; item += NT) {
    int m = item >> 11, n = item & 2047;
    int i = n >> 7, d = n & 127;
    unsigned short hh = 0, ll = 0;
    if (m < 128) {
      float gval = life[i * 16 + 15];
      float gate = gval > 0.f ? gval : 0.f;
      float v = gate * W[(size_t)(i * 16 + 15) * 16384 + m * 128 + d];
      hh = f2bf(v); ll = f2bf(v - bf2f(hh));
    }
    Rhi[item] = hh;
    Rlo[item] = ll;
  }

  // Job C: split inp -> hi/lo bf16, 8 elems/item
  for (int item = tid; item < (4096 * 512) / 8; item += NT) {
    int base = item * 8;
    float4 x = *(const float4*)(inp + base), y = *(const float4*)(inp + base + 4);
    float vals[8] = {x.x, x.y, x.z, x.w, y.x, y.y, y.z, y.w};
    union { unsigned short u[8]; uint4 v; } ph, pl;
#pragma unroll
    for (int q = 0; q < 8; ++q) {
      unsigned short h = f2bf(vals[q]);
      ph.u[q] = h;
      pl.u[q] = f2bf(vals[q] - bf2f(h));
    }
    *(uint4*)(Ihi + base) = ph.v;
    *(uint4*)(Ilo + base) = pl.v;
  }
}

// ---------------------------------------------------------------------------
// Pair step: both chains in one launch. Grid (kc, nb, chain) = (8, 64, 2).
// chain 0: P_q[kc][c][n] = sum_k Qq[c][k]*A[n][k]    (Q-chain)
// chain 1: P_r[kc][c][n] = sum_k Qr[c][k]*AT[n][k]   (R-chain, = R*A)
// Block = 3 waves; wave g owns m-rows [g*48,+48). B-tile staged to LDS via
// global_load_lds w=16 (linear dest + inverse-XOR source; read same XOR).
// Q fragments direct-global, depth-2, first prefetch above the barrier.
// 1024 blocks = 4 blocks/CU = 12 waves/CU.
// ---------------------------------------------------------------------------
__global__ __launch_bounds__(192, 2) void step_pair(
    const unsigned short* __restrict__ Ahi, const unsigned short* __restrict__ Alo,
    const unsigned short* __restrict__ AThi, const unsigned short* __restrict__ ATlo,
    const unsigned short* __restrict__ Qqhi, const unsigned short* __restrict__ Qqlo,
    const unsigned short* __restrict__ Qrhi, const unsigned short* __restrict__ Qrlo,
    float* __restrict__ Pq, float* __restrict__ Pr) {
  __shared__ __align__(16) unsigned short AS[64][256];  // rows 0-31 hi, 32-63 lo
  const int t = threadIdx.x;
  const int g = t >> 6, lane = t & 63;
  const int r16 = lane & 15, q = lane >> 4;
  const int kc = blockIdx.x;
  const int nb = blockIdx.y;
  const int chain = blockIdx.z;
  const unsigned short* Bh = chain ? AThi : Ahi;
  const unsigned short* Bl = chain ? ATlo : Alo;
  const unsigned short* Qh = chain ? Qrhi : Qqhi;
  const unsigned short* Ql = chain ? Qrlo : Qqlo;
  float* P = chain ? Pr : Pq;
  const int kbase = kc * 256;
  const int n0 = nb * 32;

  // ---- stage B-tile: 2048 16B-slots as 32 chunks of 64 (1KB each).
  for (int ch = g; ch < 32; ch += 3) {
    int s = ch * 64 + lane;
    int row = s >> 5;                       // 0..63
    int c16 = (s & 31) ^ (row & 7);         // inverse swizzle on source
    const unsigned short* src =
        (row < 32 ? Bh + (size_t)(n0 + row) * ND
                  : Bl + (size_t)(n0 + row - 32) * ND) + kbase + c16 * 8;
    __builtin_amdgcn_global_load_lds((glb_u32*)src,
                                     (lds_u32*)(&AS[0][0] + ch * 512), 16, 0, 0);
  }

  const int m0 = g * 48 + r16;
  const unsigned short* pA0h = Qh + (size_t)m0 * ND + kbase + q * 8;
  const unsigned short* pA0l = Ql + (size_t)m0 * ND + kbase + q * 8;

  // Q prefetch issued before the barrier: overlaps the stage drain.
  bf16x8 qa[2][6];
#pragma unroll
  for (int f = 0; f < 3; ++f) {
    qa[0][2 * f]     = ldg8(pA0h + f * 16 * ND);
    qa[0][2 * f + 1] = ldg8(pA0l + f * 16 * ND);
  }
  __syncthreads();   // vmcnt(0) drain covers both stage + prefetch

  const uint4* ASv = (const uint4*)&AS[0][0];   // 16B units: [row*32 + col]

  f32x4 acc[3][2];
#pragma unroll
  for (int mt = 0; mt < 3; ++mt)
#pragma unroll
    for (int nt = 0; nt < 2; ++nt) acc[mt][nt] = (f32x4){0.f, 0.f, 0.f, 0.f};

#pragma unroll
  for (int it = 0; it < 8; ++it) {
    const int cur = it & 1, nxt = cur ^ 1;
    if (it < 7) {
      const int ko = (it + 1) * 32;
#pragma unroll
      for (int f = 0; f < 3; ++f) {
        qa[nxt][2 * f]     = ldg8(pA0h + f * 16 * ND + ko);
        qa[nxt][2 * f + 1] = ldg8(pA0l + f * 16 * ND + ko);
      }
    }
    const int cx = (it * 4 + q) ^ (r16 & 7);   // swizzled 16B col
    bf16x8 b0h = __builtin_bit_cast(bf16x8, ASv[r16 * 32 + cx]);
    bf16x8 b1h = __builtin_bit_cast(bf16x8, ASv[(16 + r16) * 32 + cx]);
    bf16x8 b0l = __builtin_bit_cast(bf16x8, ASv[(32 + r16) * 32 + cx]);
    bf16x8 b1l = __builtin_bit_cast(bf16x8, ASv[(48 + r16) * 32 + cx]);

    acc[0][0] = mfma16(qa[cur][0], b0h, acc[0][0]);
    acc[0][0] = mfma16(qa[cur][1], b0h, acc[0][0]);
    acc[0][0] = mfma16(qa[cur][0], b0l, acc[0][0]);
    acc[1][0] = mfma16(qa[cur][2], b0h, acc[1][0]);
    acc[1][0] = mfma16(qa[cur][3], b0h, acc[1][0]);
    acc[1][0] = mfma16(qa[cur][2], b0l, acc[1][0]);
    acc[2][0] = mfma16(qa[cur][4], b0h, acc[2][0]);
    acc[2][0] = mfma16(qa[cur][5], b0h, acc[2][0]);
    acc[2][0] = mfma16(qa[cur][4], b0l, acc[2][0]);
    acc[0][1] = mfma16(qa[cur][0], b1h, acc[0][1]);
    acc[0][1] = mfma16(qa[cur][1], b1h, acc[0][1]);
    acc[0][1] = mfma16(qa[cur][0], b1l, acc[0][1]);
    acc[1][1] = mfma16(qa[cur][2], b1h, acc[1][1]);
    acc[1][1] = mfma16(qa[cur][3], b1h, acc[1][1]);
    acc[1][1] = mfma16(qa[cur][2], b1l, acc[1][1]);
    acc[2][1] = mfma16(qa[cur][4], b1h, acc[2][1]);
    acc[2][1] = mfma16(qa[cur][5], b1h, acc[2][1]);
    acc[2][1] = mfma16(qa[cur][4], b1l, acc[2][1]);
  }

  float* Pk = P + kc * (MT * ND);
#pragma unroll
  for (int mt = 0; mt < 3; ++mt)
#pragma unroll
    for (int nt = 0; nt < 2; ++nt) {
      int mbase = g * 48 + mt * 16 + q * 4;
      int n = n0 + nt * 16 + r16;
#pragma unroll
      for (int r = 0; r < 4; ++r)
        Pk[(mbase + r) * ND + n] = acc[mt][nt][r];
    }
}

// Sum KS partials for both chains; beta on row 128 of chain 0 only.
__global__ __launch_bounds__(256) void reduce_pair(
    const float* __restrict__ Pq, const float* __restrict__ Pr,
    const float* __restrict__ beta,
    unsigned short* __restrict__ Oqh, unsigned short* __restrict__ Oql,
    unsigned short* __restrict__ Orh, unsigned short* __restrict__ Orl) {
  int bid = blockIdx.x;                     // 0..575
  int chain = bid >= 288;
  int t = (bid - (chain ? 288 : 0)) * 256 + threadIdx.x;
  const float* P = chain ? Pr : Pq;
  unsigned short* Oh = chain ? Orh : Oqh;
  unsigned short* Ol = chain ? Orl : Oql;
  int m = t >> 9;
  int n = (t & 511) * 4;
  int idx = m * ND + n;
  const int stride = MT * ND;
  float v0 = 0.f, v1 = 0.f, v2 = 0.f, v3 = 0.f;
#pragma unroll
  for (int c = 0; c < KS; ++c) {
    float4 s = *(const float4*)(P + c * stride + idx);
    v0 += s.x; v1 += s.y; v2 += s.z; v3 += s.w;
  }
  if (!chain && m == 128) {
    float4 b4 = *(const float4*)(beta + n);
    v0 += b4.x; v1 += b4.y; v2 += b4.z; v3 += b4.w;
  }
  union { unsigned short u[4]; uint2 d; } h, l;
  float vv[4] = {v0, v1, v2, v3};
#pragma unroll
  for (int i = 0; i < 4; ++i) {
    unsigned short hh = f2bf(vv[i]);
    h.u[i] = hh;
    l.u[i] = f2bf(vv[i] - bf2f(hh));
  }
  *(uint2*)(Oh + idx) = h.d;
  *(uint2*)(Ol + idx) = l.d;
}

// ---------------------------------------------------------------------------
// Contraction: CP[kc][m][n] = sum_{k in chunk} Q5[m][k]*R5[n][k].
// Row 128 of Q5 = u -> row 128 of output = R5·u (the c-vector GEMV).
// Grid (16, 4) = 64 blocks, 128-k chunks, same 3-wave structure, 4 iters.
// ---------------------------------------------------------------------------
__global__ __launch_bounds__(192, 2) void contract_S(
    const unsigned short* __restrict__ R5h, const unsigned short* __restrict__ R5l,
    const unsigned short* __restrict__ Q5h, const unsigned short* __restrict__ Q5l,
    float* __restrict__ CP) {
  __shared__ __align__(16) unsigned short AS[64][128];  // 16KB
  const int t = threadIdx.x;
  const int g = t >> 6, lane = t & 63;
  const int r16 = lane & 15, q = lane >> 4;
  const int kc = blockIdx.x;              // 0..15, 128 k each
  const int nb = blockIdx.y;              // 0..3 (n = e in 0..127)
  const int kbase = kc * 128;
  const int n0 = nb * 32;

  // stage R5-tile: 1024 16B-slots as 16 chunks of 64 (16 slots/row)
  for (int ch = g; ch < 16; ch += 3) {
    int s = ch * 64 + lane;
    int row = s >> 4;                     // 0..63
    int c16 = (s & 15) ^ (row & 7);
    const unsigned short* src =
        (row < 32 ? R5h + (size_t)(n0 + row) * ND
                  : R5l + (size_t)(n0 + row - 32) * ND) + kbase + c16 * 8;
    __builtin_amdgcn_global_load_lds((glb_u32*)src,
                                     (lds_u32*)(&AS[0][0] + ch * 512), 16, 0, 0);
  }

  const int m0 = g * 48 + r16;
  const unsigned short* pA0h = Q5h + (size_t)m0 * ND + kbase + q * 8;
  const unsigned short* pA0l = Q5l + (size_t)m0 * ND + kbase + q * 8;

  bf16x8 qa[2][6];
#pragma unroll
  for (int f = 0; f < 3; ++f) {
    qa[0][2 * f]     = ldg8(pA0h + f * 16 * ND);
    qa[0][2 * f + 1] = ldg8(pA0l + f * 16 * ND);
  }
  __syncthreads();

  const uint4* ASv = (const uint4*)&AS[0][0];   // [row*16 + col]

  f32x4 acc[3][2];
#pragma unroll
  for (int mt = 0; mt < 3; ++mt)
#pragma unroll
    for (int nt = 0; nt < 2; ++nt) acc[mt][nt] = (f32x4){0.f, 0.f, 0.f, 0.f};

#pragma unroll
  for (int it = 0; it < 4; ++it) {
    const int cur = it & 1, nxt = cur ^ 1;
    if (it < 3) {
      const int ko = (it + 1) * 32;
#pragma unroll
      for (int f = 0; f < 3; ++f) {
        qa[nxt][2 * f]     = ldg8(pA0h + f * 16 * ND + ko);
        qa[nxt][2 * f + 1] = ldg8(pA0l + f * 16 * ND + ko);
      }
    }
    const int cx = (it * 4 + q) ^ (r16 & 7);   // 0..15 16B cols
    bf16x8 b0h = __builtin_bit_cast(bf16x8, ASv[r16 * 16 + cx]);
    bf16x8 b1h = __builtin_bit_cast(bf16x8, ASv[(16 + r16) * 16 + cx]);
    bf16x8 b0l = __builtin_bit_cast(bf16x8, ASv[(32 + r16) * 16 + cx]);
    bf16x8 b1l = __builtin_bit_cast(bf16x8, ASv[(48 + r16) * 16 + cx]);

    acc[0][0] = mfma16(qa[cur][0], b0h, acc[0][0]);
    acc[0][0] = mfma16(qa[cur][1], b0h, acc[0][0]);
    acc[0][0] = mfma16(qa[cur][0], b0l, acc[0][0]);
    acc[1][0] = mfma16(qa[cur][2], b0h, acc[1][0]);
    acc[1][0] = mfma16(qa[cur][3], b0h, acc[1][0]);
    acc[1][0] = mfma16(qa[cur][2], b0l, acc[1][0]);
    acc[2][0] = mfma16(qa[cur][4], b0h, acc[2][0]);
    acc[2][0] = mfma16(qa[cur][5], b0h, acc[2][0]);
    acc[2][0] = mfma16(qa[cur][4], b0l, acc[2][0]);
    acc[0][1] = mfma16(qa[cur][0], b1h, acc[0][1]);
    acc[0][1] = mfma16(qa[cur][1], b1h, acc[0][1]);
    acc[0][1] = mfma16(qa[cur][0], b1l, acc[0][1]);
    acc[1][1] = mfma16(qa[cur][2], b1h, acc[1][1]);
    acc[1][1] = mfma16(qa[cur][3], b1h, acc[1][1]);
    acc[1][1] = mfma16(qa[cur][2], b1l, acc[1][1]);
    acc[2][1] = mfma16(qa[cur][4], b1h, acc[2][1]);
    acc[2][1] = mfma16(qa[cur][5], b1h, acc[2][1]);
    acc[2][1] = mfma16(qa[cur][4], b1l, acc[2][1]);
  }

  float* Pk = CP + kc * (MT * 128);
#pragma unroll
  for (int mt = 0; mt < 3; ++mt)
#pragma unroll
    for (int nt = 0; nt < 2; ++nt) {
      int mbase = g * 48 + mt * 16 + q * 4;
      int n = n0 + nt * 16 + r16;
#pragma unroll
      for (int r = 0; r < 4; ++r)
        Pk[(mbase + r) * 128 + n] = acc[mt][nt][r];
    }
}

// Reduce contraction partials: St[d][e] = S[e,d]; gv[e] = u[1920+e] + (R5 u)[e]
__global__ __launch_bounds__(256) void extract_Sc(
    const float* __restrict__ CP,
    const unsigned short* __restrict__ Q5h, const unsigned short* __restrict__ Q5l,
    float* __restrict__ St, float* __restrict__ gv) {
  int t = blockIdx.x * 256 + threadIdx.x;
  const int PSTR = MT * 128;
  if (t < 16384) {
    int d = t >> 7, e = t & 127;
    float v = 0.f;
#pragma unroll
    for (int c = 0; c < CKS; ++c) v += CP[c * PSTR + d * 128 + e];
    St[t] = v;                                   // St[d][e] = S[e,d]
  } else if (t < 16512) {
    int e = t - 16384;
    float v = bf2f(Q5h[128 * ND + 1920 + e]) + bf2f(Q5l[128 * ND + 1920 + e]);
#pragma unroll
    for (int c = 0; c < CKS; ++c) v += CP[c * PSTR + 128 * 128 + e];
    gv[e] = v;
  }
}

// ---------------------------------------------------------------------------
// Tail (2 wide kernels, fp32-exact S path).
// ---------------------------------------------------------------------------
__global__ __launch_bounds__(256) void tail_T1g(
    const float* __restrict__ St, const float* __restrict__ Wpre,
    const float* __restrict__ bpre, float* __restrict__ T1,
    float* __restrict__ gv) {
  int t = blockIdx.x * 256 + threadIdx.x;
  if (t < 65536) {
    int e = t >> 9, ic = t & 511;
    float s = 0.f;
    for (int d = 0; d < 128; ++d) s += St[d * 128 + e] * Wpre[d * 512 + ic];
    T1[t] = s;
  } else if (t < 65664) {
    int e = t - 65536;
    float s = gv[e];
    for (int d = 0; d < 128; ++d) s += St[d * 128 + e] * bpre[d];
    gv[e] = s;                                   // only this thread touches e
  }
}

__global__ __launch_bounds__(256) void tail_Weff(
    const float* __restrict__ Wpost, const float* __restrict__ T1,
    const float* __restrict__ gv, const float* __restrict__ bpost,
    unsigned short* __restrict__ Whi, unsigned short* __restrict__ Wlo,
    float* __restrict__ beff) {
  int t = blockIdx.x * 256 + threadIdx.x;
  if (t < 262144) {
    int o = t >> 9, ic = t & 511;
    float s = 0.f;
    for (int e = 0; e < 128; ++e) s += Wpost[o * 128 + e] * T1[e * 512 + ic];
    unsigned short h = f2bf(s);
    Whi[t] = h;
    Wlo[t] = f2bf(s - bf2f(h));
  } else if (t < 262656) {
    int o = t - 262144;
    float s = bpost[o];
    for (int e = 0; e < 128; ++e) s += Wpost[o * 128 + e] * gv[e];
    beff[o] = s;
  }
}

// ---------------------------------------------------------------------------
// out[4096,512] = inp @ Weff^T + beff. M=4096,N=512,K=512, split bf16.
// Block tile 64(M) x 128(N): grid (64,4), 4 waves; wave w owns n-cols
// [32w,32w+32). Double-buffered LDS, single barrier per k-tile: issue next
// tile's global loads, compute current (hides latency), write regs to alt
// buffer, barrier. 17 barriers vs 32.
// ---------------------------------------------------------------------------
__global__ __launch_bounds__(256) void final_gemm(
    const unsigned short* __restrict__ Ihi, const unsigned short* __restrict__ Ilo,
    const unsigned short* __restrict__ Whi, const unsigned short* __restrict__ Wlo,
    const float* __restrict__ beff, float* __restrict__ out) {
  __shared__ __align__(16) unsigned short Is_hi[2][64][40], Is_lo[2][64][40];
  __shared__ __align__(16) unsigned short Ws_hi[2][128][40], Ws_lo[2][128][40];
  const int t = threadIdx.x;
  const int mb = blockIdx.x, nb = blockIdx.y;
  const int w = t >> 6, lane = t & 63;
  const int r16 = lane & 15, q = lane >> 4;

  uint4 stg[6];
  auto load_regs = [&](int kc) {
    const int k0 = kc * 32;
#pragma unroll
    for (int rpt = 0; rpt < 6; ++rpt) {
      int slot = t + rpt * 256;
      if (slot < 512) {
        int arr = slot >> 8, s = slot & 255;
        int row = s >> 2, off = (s & 3) * 8;
        const unsigned short* src = arr ? Ilo : Ihi;
        stg[rpt] = *(const uint4*)(src + (mb * 64 + row) * 512 + k0 + off);
      } else {
        int s = slot - 512;
        int arr = s >> 9, s2 = s & 511;
        int row = s2 >> 2, off = (s2 & 3) * 8;
        const unsigned short* src = arr ? Wlo : Whi;
        stg[rpt] = *(const uint4*)(src + (nb * 128 + row) * 512 + k0 + off);
      }
    }
  };
  auto store_lds = [&](int b) {
#pragma unroll
    for (int rpt = 0; rpt < 6; ++rpt) {
      int slot = t + rpt * 256;
      if (slot < 512) {
        int arr = slot >> 8, s = slot & 255;
        int row = s >> 2, off = (s & 3) * 8;
        unsigned short* dst = arr ? &Is_lo[b][row][off] : &Is_hi[b][row][off];
        *(uint4*)dst = stg[rpt];
      } else {
        int s = slot - 512;
        int arr = s >> 9, s2 = s & 511;
        int row = s2 >> 2, off = (s2 & 3) * 8;
        unsigned short* dst = arr ? &Ws_lo[b][row][off] : &Ws_hi[b][row][off];
        *(uint4*)dst = stg[rpt];
      }
    }
  };

  f32x4 acc[4][2];
#pragma unroll
  for (int x = 0; x < 4; ++x)
#pragma unroll
    for (int b = 0; b < 2; ++b) acc[x][b] = (f32x4){0.f, 0.f, 0.f, 0.f};

  load_regs(0);
  store_lds(0);
  __syncthreads();

  for (int kc = 0; kc < 16; ++kc) {
    const int cur = kc & 1;
    if (kc < 15) load_regs(kc + 1);          // async: latency hides under MFMA

    bf16x8 bh0 = __builtin_bit_cast(bf16x8, *(const uint4*)&Ws_hi[cur][w * 32 + r16][q * 8]);
    bf16x8 bl0 = __builtin_bit_cast(bf16x8, *(const uint4*)&Ws_lo[cur][w * 32 + r16][q * 8]);
    bf16x8 bh1 = __builtin_bit_cast(bf16x8, *(const uint4*)&Ws_hi[cur][w * 32 + 16 + r16][q * 8]);
    bf16x8 bl1 = __builtin_bit_cast(bf16x8, *(const uint4*)&Ws_lo[cur][w * 32 + 16 + r16][q * 8]);
#pragma unroll
    for (int mt = 0; mt < 4; ++mt) {
      bf16x8 ah = __builtin_bit_cast(bf16x8, *(const uint4*)&Is_hi[cur][mt * 16 + r16][q * 8]);
      bf16x8 al = __builtin_bit_cast(bf16x8, *(const uint4*)&Is_lo[cur][mt * 16 + r16][q * 8]);
      acc[mt][0] = mfma16(ah, bh0, acc[mt][0]);
      acc[mt][0] = mfma16(al, bh0, acc[mt][0]);
      acc[mt][0] = mfma16(ah, bl0, acc[mt][0]);
      acc[mt][1] = mfma16(ah, bh1, acc[mt][1]);
      acc[mt][1] = mfma16(al, bh1, acc[mt][1]);
      acc[mt][1] = mfma16(ah, bl1, acc[mt][1]);
    }

    if (kc < 15) store_lds(cur ^ 1);
    __syncthreads();
  }

#pragma unroll
  for (int mt = 0; mt < 4; ++mt)
#pragma unroll
    for (int nt = 0; nt < 2; ++nt) {
      int n = nb * 128 + w * 32 + nt * 16 + r16;
      float bv = beff[n];
#pragma unroll
      for (int r = 0; r < 4; ++r) {
        int m = mb * 64 + mt * 16 + q * 4 + r;
        out[m * 512 + n] = acc[mt][nt][r] + bv;
      }
    }
}

extern "C" void kernel_launch(void* const* d_in, const int* in_sizes, int n_in,
                              void* d_out, int out_size, void* d_ws, size_t ws_size,
                              hipStream_t stream) {
  const float* inp   = (const float*)d_in[0];
  const float* Wpre  = (const float*)d_in[1];
  const float* bpre  = (const float*)d_in[2];
  const float* W     = (const float*)d_in[3];
  const float* bl    = (const float*)d_in[4];
  const float* life  = (const float*)d_in[5];
  const float* Wpost = (const float*)d_in[6];
  const float* bpost = (const float*)d_in[7];
  float* out = (float*)d_out;

  char* p = (char*)d_ws;
  auto alloc = [&](size_t bytes) {
    char* r = p;
    p += (bytes + 255) & ~(size_t)255;
    return r;
  };
  unsigned short* Ahi  = (unsigned short*)alloc((size_t)ND * ND * 2);
  unsigned short* Alo  = (unsigned short*)alloc((size_t)ND * ND * 2);
  unsigned short* AThi = (unsigned short*)alloc((size_t)ND * ND * 2);
  unsigned short* ATlo = (unsigned short*)alloc((size_t)ND * ND * 2);
  unsigned short* QqAh = (unsigned short*)alloc((size_t)MT * ND * 2);
  unsigned short* QqAl = (unsigned short*)alloc((size_t)MT * ND * 2);
  unsigned short* QqBh = (unsigned short*)alloc((size_t)MT * ND * 2);
  unsigned short* QqBl = (unsigned short*)alloc((size_t)MT * ND * 2);
  unsigned short* QrAh = (unsigned short*)alloc((size_t)MT * ND * 2);
  unsigned short* QrAl = (unsigned short*)alloc((size_t)MT * ND * 2);
  unsigned short* QrBh = (unsigned short*)alloc((size_t)MT * ND * 2);
  unsigned short* QrBl = (unsigned short*)alloc((size_t)MT * ND * 2);
  float* beta = (float*)alloc(ND * 4);
  float* Pq   = (float*)alloc((size_t)KS * MT * ND * 4);
  float* Pr   = (float*)alloc((size_t)KS * MT * ND * 4);
  float* CP   = (float*)alloc((size_t)CKS * MT * 128 * 4);
  float* St   = (float*)alloc(128 * 128 * 4);
  float* gv   = (float*)alloc(128 * 4);
  float* T1   = (float*)alloc(128 * 512 * 4);
  float* beff = (float*)alloc(512 * 4);
  unsigned short* Whi = (unsigned short*)alloc(512 * 512 * 2);
  unsigned short* Wlo = (unsigned short*)alloc(512 * 512 * 2);
  unsigned short* Ihi = (unsigned short*)alloc((size_t)4096 * 512 * 2);
  unsigned short* Ilo = (unsigned short*)alloc((size_t)4096 * 512 * 2);

  build_all<<<1024, 256, 0, stream>>>(W, life, bl, inp, Ahi, Alo, AThi, ATlo,
                                      QqAh, QqAl, QrAh, QrAl, beta, Ihi, Ilo);

  // 4 paired multiplies: both chains advance A^1 -> A^5
  const unsigned short *qqh = QqAh, *qql = QqAl, *qrh = QrAh, *qrl = QrAl;
  unsigned short *oqh = QqBh, *oql = QqBl, *orh = QrBh, *orl = QrBl;
  for (int s = 0; s < 4; ++s) {
    step_pair<<<dim3(KS, 64, 2), 192, 0, stream>>>(
        Ahi, Alo, AThi, ATlo, qqh, qql, qrh, qrl, Pq, Pr);
    reduce_pair<<<576, 256, 0, stream>>>(Pq, Pr, beta, oqh, oql, orh, orl);
    const unsigned short* t1 = qqh; qqh = oqh; oqh = (unsigned short*)t1;
    const unsigned short* t2 = qql; qql = oql; oql = (unsigned short*)t2;
    const unsigned short* t3 = qrh; qrh = orh; orh = (unsigned short*)t3;
    const unsigned short* t4 = qrl; qrl = orl; orl = (unsigned short*)t4;
  }

  contract_S<<<dim3(CKS, 4), 192, 0, stream>>>(qrh, qrl, qqh, qql, CP);
  extract_Sc<<<65, 256, 0, stream>>>(CP, qqh, qql, St, gv);
  tail_T1g<<<257, 256, 0, stream>>>(St, Wpre, bpre, T1, gv);
  tail_Weff<<<1026, 256, 0, stream>>>(Wpost, T1, gv, bpost, Whi, Wlo, beff);
  final_gemm<<<dim3(64, 4), 256, 0, stream>>>(Ihi, Ilo, Whi, Wlo, beff, out);
}

// Round 12
// 253.578 us; speedup vs baseline: 1.2742x; 1.2742x over previous
//
#include <hip/hip_runtime.h>

// ---------------------------------------------------------------------------
// Algebraic collapse: the scan is linear & batch-independent.
//   m_{t+1} = A m_t + beta,  A[(j,e),(i,d)] = gate[i,j]*W[i,j,e,d]
//   out = inp @ Weff^T + beff,  Weff = Wpost * S * Wpre,
//   S = (A^10)[block15, block0],  c = (sum_{k<10} A^k beta)[block15]
// Round 14: revert final_gemm to the R10 simple-staging version (R11's
// reg-staged double-buffer spilled: VGPR=88 w/ 13MB scratch writes -> 87us).
// Keep R11's fused A+AT build (neutral/positive, -1 dispatch) and the
// A^5*A^5 dual-chain structure (254us verified). Dispatches: 14.
// ---------------------------------------------------------------------------

typedef __bf16 bf16x8 __attribute__((ext_vector_type(8)));
typedef float f32x4 __attribute__((ext_vector_type(4)));
typedef __attribute__((address_space(3))) unsigned int lds_u32;
typedef const __attribute__((address_space(1))) unsigned int glb_u32;

__device__ __forceinline__ unsigned short f2bf(float x) {
  unsigned int u = __float_as_uint(x);
  u += 0x7FFFu + ((u >> 16) & 1u);   // round-to-nearest-even
  return (unsigned short)(u >> 16);
}
__device__ __forceinline__ float bf2f(unsigned short s) {
  return __uint_as_float(((unsigned int)s) << 16);
}
__device__ __forceinline__ bf16x8 ldg8(const unsigned short* p) {
  return __builtin_bit_cast(bf16x8, *(const uint4*)p);
}
__device__ __forceinline__ f32x4 mfma16(bf16x8 a, bf16x8 b, f32x4 c) {
  return __builtin_amdgcn_mfma_f32_16x16x32_bf16(a, b, c, 0, 0, 0);
}

#define ND 2048   // num*dim
#define MT 144    // padded iterate rows (129 used: 128 propagator + 1 bias)
#define KS 8      // split-K chunks (256 k each)
#define CKS 16    // contraction split-K chunks (128 k each)

// ---------------------------------------------------------------------------
// Phase 0 (fused): tiled A+AT build (LDS transpose, W read once), Q-chain
// init Q1 (+beta), R-chain init R1, split inp. 1024 blocks; the tile job
// runs exactly 4 uniform iterations/block (4096 tiles) so barriers are safe.
// ---------------------------------------------------------------------------
__global__ __launch_bounds__(256) void build_all(
    const float* __restrict__ W, const float* __restrict__ life,
    const float* __restrict__ bl, const float* __restrict__ inp,
    unsigned short* __restrict__ Ahi, unsigned short* __restrict__ Alo,
    unsigned short* __restrict__ AThi, unsigned short* __restrict__ ATlo,
    unsigned short* __restrict__ Qhi, unsigned short* __restrict__ Qlo,
    unsigned short* __restrict__ Rhi, unsigned short* __restrict__ Rlo,
    float* __restrict__ beta,
    unsigned short* __restrict__ Ihi, unsigned short* __restrict__ Ilo) {
  __shared__ unsigned short Th[32][36], Tl[32][36];
  const int tid = blockIdx.x * 256 + threadIdx.x;
  const int NT = gridDim.x * 256;
  const int t = threadIdx.x;

  // Job A: per 32x32 tile of A: read W, scale+split, write A and AT.
  {
    const int r = t >> 3;              // 0..31 row within tile
    const int c4 = (t & 7) * 4;        // 0,4,...,28
    for (int tt = blockIdx.x; tt < 4096; tt += gridDim.x) {
      int nt = tt & 63, kt = tt >> 6;
      int j = nt >> 2, e0 = (nt & 3) * 32;
      int i = kt >> 2, d0 = (kt & 3) * 32;
      float gval = life[i * 16 + j];
      float gate = gval > 0.f ? gval : 0.f;
      const float* src = W + ((size_t)(i * 16 + j) * 16384 + (e0 + r) * 128 + d0 + c4);
      float4 v = *(const float4*)src;
      float vals[4] = {v.x, v.y, v.z, v.w};
      union { unsigned short u[4]; uint2 d2; } oh, ol;
#pragma unroll
      for (int x = 0; x < 4; ++x) {
        float s = gate * vals[x];
        oh.u[x] = f2bf(s);
        ol.u[x] = f2bf(s - bf2f(oh.u[x]));
      }
      size_t aidx = (size_t)(j * 128 + e0 + r) * ND + i * 128 + d0 + c4;
      *(uint2*)(Ahi + aidx) = oh.d2;
      *(uint2*)(Alo + aidx) = ol.d2;
      __syncthreads();                 // protect prior iteration's LDS reads
#pragma unroll
      for (int x = 0; x < 4; ++x) { Th[r][c4 + x] = oh.u[x]; Tl[r][c4 + x] = ol.u[x]; }
      __syncthreads();
      union { unsigned short u[4]; uint2 d2; } th, tl;
#pragma unroll
      for (int x = 0; x < 4; ++x) { th.u[x] = Th[c4 + x][r]; tl.u[x] = Tl[c4 + x][r]; }
      size_t tidx = (size_t)(i * 128 + d0 + r) * ND + j * 128 + e0 + c4;
      *(uint2*)(AThi + tidx) = th.d2;
      *(uint2*)(ATlo + tidx) = tl.d2;
    }
  }

  // Job B: Q1[c=d][n=(j,e)] = gate[0,j]*W[0,j,e,d]; row 128 = beta; rest 0.
  for (int item = tid; item < MT * ND; item += NT) {
    int m = item >> 11, n = item & 2047;
    int j = n >> 7, e = n & 127;
    unsigned short hh = 0, ll = 0;
    if (m < 128) {
      float gval = life[j];                         // i = 0
      float gate = gval > 0.f ? gval : 0.f;
      float v = gate * W[j * 16384 + e * 128 + m];
      hh = f2bf(v); ll = f2bf(v - bf2f(hh));
    } else if (m == 128) {
      float s = 0.f;
#pragma unroll
      for (int i = 0; i < 16; ++i) {
        float gval = life[i * 16 + j];
        float gate = gval > 0.f ? gval : 0.f;
        s += gate * bl[(i * 16 + j) * 128 + e];
      }
      beta[n] = s;
      hh = f2bf(s); ll = f2bf(s - bf2f(hh));
    }
    Qhi[item] = hh;
    Qlo[item] = ll;
  }

  // Job B2: R1[r][n=(i,d)] = A[1920+r][n] = gate[i,15]*W[i,15,r,d]; rows>=128: 0
  for (int item = tid; item < MT * ND; item += NT) {
    int m = item >> 11, n = item & 2047;
    int i = n >> 7, d = n & 127;
    unsigned short hh = 0, ll = 0;
    if (m < 128) {
      float gval = life[i * 16 + 15];
      float gate = gval > 0.f ? gval : 0.f;
      float v = gate * W[(size_t)(i * 16 + 15) * 16384 + m * 128 + d];
      hh = f2bf(v); ll = f2bf(v - bf2f(hh));
    }
    Rhi[item] = hh;
    Rlo[item] = ll;
  }

  // Job C: split inp -> hi/lo bf16, 8 elems/item
  for (int item = tid; item < (4096 * 512) / 8; item += NT) {
    int base = item * 8;
    float4 x = *(const float4*)(inp + base), y = *(const float4*)(inp + base + 4);
    float vals[8] = {x.x, x.y, x.z, x.w, y.x, y.y, y.z, y.w};
    union { unsigned short u[8]; uint4 v; } ph, pl;
#pragma unroll
    for (int q = 0; q < 8; ++q) {
      unsigned short h = f2bf(vals[q]);
      ph.u[q] = h;
      pl.u[q] = f2bf(vals[q] - bf2f(h));
    }
    *(uint4*)(Ihi + base) = ph.v;
    *(uint4*)(Ilo + base) = pl.v;
  }
}

// ---------------------------------------------------------------------------
// Pair step: both chains in one launch. Grid (kc, nb, chain) = (8, 64, 2).
// chain 0: P_q[kc][c][n] = sum_k Qq[c][k]*A[n][k]    (Q-chain)
// chain 1: P_r[kc][c][n] = sum_k Qr[c][k]*AT[n][k]   (R-chain, = R*A)
// Block = 3 waves; wave g owns m-rows [g*48,+48). B-tile staged to LDS via
// global_load_lds w=16 (linear dest + inverse-XOR source; read same XOR).
// Q fragments direct-global, depth-2, first prefetch above the barrier.
// 1024 blocks = 4 blocks/CU = 12 waves/CU.
// ---------------------------------------------------------------------------
__global__ __launch_bounds__(192, 2) void step_pair(
    const unsigned short* __restrict__ Ahi, const unsigned short* __restrict__ Alo,
    const unsigned short* __restrict__ AThi, const unsigned short* __restrict__ ATlo,
    const unsigned short* __restrict__ Qqhi, const unsigned short* __restrict__ Qqlo,
    const unsigned short* __restrict__ Qrhi, const unsigned short* __restrict__ Qrlo,
    float* __restrict__ Pq, float* __restrict__ Pr) {
  __shared__ __align__(16) unsigned short AS[64][256];  // rows 0-31 hi, 32-63 lo
  const int t = threadIdx.x;
  const int g = t >> 6, lane = t & 63;
  const int r16 = lane & 15, q = lane >> 4;
  const int kc = blockIdx.x;
  const int nb = blockIdx.y;
  const int chain = blockIdx.z;
  const unsigned short* Bh = chain ? AThi : Ahi;
  const unsigned short* Bl = chain ? ATlo : Alo;
  const unsigned short* Qh = chain ? Qrhi : Qqhi;
  const unsigned short* Ql = chain ? Qrlo : Qqlo;
  float* P = chain ? Pr : Pq;
  const int kbase = kc * 256;
  const int n0 = nb * 32;

  // ---- stage B-tile: 2048 16B-slots as 32 chunks of 64 (1KB each).
  for (int ch = g; ch < 32; ch += 3) {
    int s = ch * 64 + lane;
    int row = s >> 5;                       // 0..63
    int c16 = (s & 31) ^ (row & 7);         // inverse swizzle on source
    const unsigned short* src =
        (row < 32 ? Bh + (size_t)(n0 + row) * ND
                  : Bl + (size_t)(n0 + row - 32) * ND) + kbase + c16 * 8;
    __builtin_amdgcn_global_load_lds((glb_u32*)src,
                                     (lds_u32*)(&AS[0][0] + ch * 512), 16, 0, 0);
  }

  const int m0 = g * 48 + r16;
  const unsigned short* pA0h = Qh + (size_t)m0 * ND + kbase + q * 8;
  const unsigned short* pA0l = Ql + (size_t)m0 * ND + kbase + q * 8;

  // Q prefetch issued before the barrier: overlaps the stage drain.
  bf16x8 qa[2][6];
#pragma unroll
  for (int f = 0; f < 3; ++f) {
    qa[0][2 * f]     = ldg8(pA0h + f * 16 * ND);
    qa[0][2 * f + 1] = ldg8(pA0l + f * 16 * ND);
  }
  __syncthreads();   // vmcnt(0) drain covers both stage + prefetch

  const uint4* ASv = (const uint4*)&AS[0][0];   // 16B units: [row*32 + col]

  f32x4 acc[3][2];
#pragma unroll
  for (int mt = 0; mt < 3; ++mt)
#pragma unroll
    for (int nt = 0; nt < 2; ++nt) acc[mt][nt] = (f32x4){0.f, 0.f, 0.f, 0.f};

#pragma unroll
  for (int it = 0; it < 8; ++it) {
    const int cur = it & 1, nxt = cur ^ 1;
    if (it < 7) {
      const int ko = (it + 1) * 32;
#pragma unroll
      for (int f = 0; f < 3; ++f) {
        qa[nxt][2 * f]     = ldg8(pA0h + f * 16 * ND + ko);
        qa[nxt][2 * f + 1] = ldg8(pA0l + f * 16 * ND + ko);
      }
    }
    const int cx = (it * 4 + q) ^ (r16 & 7);   // swizzled 16B col
    bf16x8 b0h = __builtin_bit_cast(bf16x8, ASv[r16 * 32 + cx]);
    bf16x8 b1h = __builtin_bit_cast(bf16x8, ASv[(16 + r16) * 32 + cx]);
    bf16x8 b0l = __builtin_bit_cast(bf16x8, ASv[(32 + r16) * 32 + cx]);
    bf16x8 b1l = __builtin_bit_cast(bf16x8, ASv[(48 + r16) * 32 + cx]);

    acc[0][0] = mfma16(qa[cur][0], b0h, acc[0][0]);
    acc[0][0] = mfma16(qa[cur][1], b0h, acc[0][0]);
    acc[0][0] = mfma16(qa[cur][0], b0l, acc[0][0]);
    acc[1][0] = mfma16(qa[cur][2], b0h, acc[1][0]);
    acc[1][0] = mfma16(qa[cur][3], b0h, acc[1][0]);
    acc[1][0] = mfma16(qa[cur][2], b0l, acc[1][0]);
    acc[2][0] = mfma16(qa[cur][4], b0h, acc[2][0]);
    acc[2][0] = mfma16(qa[cur][5], b0h, acc[2][0]);
    acc[2][0] = mfma16(qa[cur][4], b0l, acc[2][0]);
    acc[0][1] = mfma16(qa[cur][0], b1h, acc[0][1]);
    acc[0][1] = mfma16(qa[cur][1], b1h, acc[0][1]);
    acc[0][1] = mfma16(qa[cur][0], b1l, acc[0][1]);
    acc[1][1] = mfma16(qa[cur][2], b1h, acc[1][1]);
    acc[1][1] = mfma16(qa[cur][3], b1h, acc[1][1]);
    acc[1][1] = mfma16(qa[cur][2], b1l, acc[1][1]);
    acc[2][1] = mfma16(qa[cur][4], b1h, acc[2][1]);
    acc[2][1] = mfma16(qa[cur][5], b1h, acc[2][1]);
    acc[2][1] = mfma16(qa[cur][4], b1l, acc[2][1]);
  }

  float* Pk = P + kc * (MT * ND);
#pragma unroll
  for (int mt = 0; mt < 3; ++mt)
#pragma unroll
    for (int nt = 0; nt < 2; ++nt) {
      int mbase = g * 48 + mt * 16 + q * 4;
      int n = n0 + nt * 16 + r16;
#pragma unroll
      for (int r = 0; r < 4; ++r)
        Pk[(mbase + r) * ND + n] = acc[mt][nt][r];
    }
}

// Sum KS partials for both chains; beta on row 128 of chain 0 only.
__global__ __launch_bounds__(256) void reduce_pair(
    const float* __restrict__ Pq, const float* __restrict__ Pr,
    const float* __restrict__ beta,
    unsigned short* __restrict__ Oqh, unsigned short* __restrict__ Oql,
    unsigned short* __restrict__ Orh, unsigned short* __restrict__ Orl) {
  int bid = blockIdx.x;                     // 0..575
  int chain = bid >= 288;
  int t = (bid - (chain ? 288 : 0)) * 256 + threadIdx.x;
  const float* P = chain ? Pr : Pq;
  unsigned short* Oh = chain ? Orh : Oqh;
  unsigned short* Ol = chain ? Orl : Oql;
  int m = t >> 9;
  int n = (t & 511) * 4;
  int idx = m * ND + n;
  const int stride = MT * ND;
  float v0 = 0.f, v1 = 0.f, v2 = 0.f, v3 = 0.f;
#pragma unroll
  for (int c = 0; c < KS; ++c) {
    float4 s = *(const float4*)(P + c * stride + idx);
    v0 += s.x; v1 += s.y; v2 += s.z; v3 += s.w;
  }
  if (!chain && m == 128) {
    float4 b4 = *(const float4*)(beta + n);
    v0 += b4.x; v1 += b4.y; v2 += b4.z; v3 += b4.w;
  }
  union { unsigned short u[4]; uint2 d; } h, l;
  float vv[4] = {v0, v1, v2, v3};
#pragma unroll
  for (int i = 0; i < 4; ++i) {
    unsigned short hh = f2bf(vv[i]);
    h.u[i] = hh;
    l.u[i] = f2bf(vv[i] - bf2f(hh));
  }
  *(uint2*)(Oh + idx) = h.d;
  *(uint2*)(Ol + idx) = l.d;
}

// ---------------------------------------------------------------------------
// Contraction: CP[kc][m][n] = sum_{k in chunk} Q5[m][k]*R5[n][k].
// Row 128 of Q5 = u -> row 128 of output = R5·u (the c-vector GEMV).
// Grid (16, 4) = 64 blocks, 128-k chunks, same 3-wave structure, 4 iters.
// ---------------------------------------------------------------------------
__global__ __launch_bounds__(192, 2) void contract_S(
    const unsigned short* __restrict__ R5h, const unsigned short* __restrict__ R5l,
    const unsigned short* __restrict__ Q5h, const unsigned short* __restrict__ Q5l,
    float* __restrict__ CP) {
  __shared__ __align__(16) unsigned short AS[64][128];  // 16KB
  const int t = threadIdx.x;
  const int g = t >> 6, lane = t & 63;
  const int r16 = lane & 15, q = lane >> 4;
  const int kc = blockIdx.x;              // 0..15, 128 k each
  const int nb = blockIdx.y;              // 0..3 (n = e in 0..127)
  const int kbase = kc * 128;
  const int n0 = nb * 32;

  // stage R5-tile: 1024 16B-slots as 16 chunks of 64 (16 slots/row)
  for (int ch = g; ch < 16; ch += 3) {
    int s = ch * 64 + lane;
    int row = s >> 4;                     // 0..63
    int c16 = (s & 15) ^ (row & 7);
    const unsigned short* src =
        (row < 32 ? R5h + (size_t)(n0 + row) * ND
                  : R5l + (size_t)(n0 + row - 32) * ND) + kbase + c16 * 8;
    __builtin_amdgcn_global_load_lds((glb_u32*)src,
                                     (lds_u32*)(&AS[0][0] + ch * 512), 16, 0, 0);
  }

  const int m0 = g * 48 + r16;
  const unsigned short* pA0h = Q5h + (size_t)m0 * ND + kbase + q * 8;
  const unsigned short* pA0l = Q5l + (size_t)m0 * ND + kbase + q * 8;

  bf16x8 qa[2][6];
#pragma unroll
  for (int f = 0; f < 3; ++f) {
    qa[0][2 * f]     = ldg8(pA0h + f * 16 * ND);
    qa[0][2 * f + 1] = ldg8(pA0l + f * 16 * ND);
  }
  __syncthreads();

  const uint4* ASv = (const uint4*)&AS[0][0];   // [row*16 + col]

  f32x4 acc[3][2];
#pragma unroll
  for (int mt = 0; mt < 3; ++mt)
#pragma unroll
    for (int nt = 0; nt < 2; ++nt) acc[mt][nt] = (f32x4){0.f, 0.f, 0.f, 0.f};

#pragma unroll
  for (int it = 0; it < 4; ++it) {
    const int cur = it & 1, nxt = cur ^ 1;
    if (it < 3) {
      const int ko = (it + 1) * 32;
#pragma unroll
      for (int f = 0; f < 3; ++f) {
        qa[nxt][2 * f]     = ldg8(pA0h + f * 16 * ND + ko);
        qa[nxt][2 * f + 1] = ldg8(pA0l + f * 16 * ND + ko);
      }
    }
    const int cx = (it * 4 + q) ^ (r16 & 7);   // 0..15 16B cols
    bf16x8 b0h = __builtin_bit_cast(bf16x8, ASv[r16 * 16 + cx]);
    bf16x8 b1h = __builtin_bit_cast(bf16x8, ASv[(16 + r16) * 16 + cx]);
    bf16x8 b0l = __builtin_bit_cast(bf16x8, ASv[(32 + r16) * 16 + cx]);
    bf16x8 b1l = __builtin_bit_cast(bf16x8, ASv[(48 + r16) * 16 + cx]);

    acc[0][0] = mfma16(qa[cur][0], b0h, acc[0][0]);
    acc[0][0] = mfma16(qa[cur][1], b0h, acc[0][0]);
    acc[0][0] = mfma16(qa[cur][0], b0l, acc[0][0]);
    acc[1][0] = mfma16(qa[cur][2], b0h, acc[1][0]);
    acc[1][0] = mfma16(qa[cur][3], b0h, acc[1][0]);
    acc[1][0] = mfma16(qa[cur][2], b0l, acc[1][0]);
    acc[2][0] = mfma16(qa[cur][4], b0h, acc[2][0]);
    acc[2][0] = mfma16(qa[cur][5], b0h, acc[2][0]);
    acc[2][0] = mfma16(qa[cur][4], b0l, acc[2][0]);
    acc[0][1] = mfma16(qa[cur][0], b1h, acc[0][1]);
    acc[0][1] = mfma16(qa[cur][1], b1h, acc[0][1]);
    acc[0][1] = mfma16(qa[cur][0], b1l, acc[0][1]);
    acc[1][1] = mfma16(qa[cur][2], b1h, acc[1][1]);
    acc[1][1] = mfma16(qa[cur][3], b1h, acc[1][1]);
    acc[1][1] = mfma16(qa[cur][2], b1l, acc[1][1]);
    acc[2][1] = mfma16(qa[cur][4], b1h, acc[2][1]);
    acc[2][1] = mfma16(qa[cur][5], b1h, acc[2][1]);
    acc[2][1] = mfma16(qa[cur][4], b1l, acc[2][1]);
  }

  float* Pk = CP + kc * (MT * 128);
#pragma unroll
  for (int mt = 0; mt < 3; ++mt)
#pragma unroll
    for (int nt = 0; nt < 2; ++nt) {
      int mbase = g * 48 + mt * 16 + q * 4;
      int n = n0 + nt * 16 + r16;
#pragma unroll
      for (int r = 0; r < 4; ++r)
        Pk[(mbase + r) * 128 + n] = acc[mt][nt][r];
    }
}

// Reduce contraction partials: St[d][e] = S[e,d]; gv[e] = u[1920+e] + (R5 u)[e]
__global__ __launch_bounds__(256) void extract_Sc(
    const float* __restrict__ CP,
    const unsigned short* __restrict__ Q5h, const unsigned short* __restrict__ Q5l,
    float* __restrict__ St, float* __restrict__ gv) {
  int t = blockIdx.x * 256 + threadIdx.x;
  const int PSTR = MT * 128;
  if (t < 16384) {
    int d = t >> 7, e = t & 127;
    float v = 0.f;
#pragma unroll
    for (int c = 0; c < CKS; ++c) v += CP[c * PSTR + d * 128 + e];
    St[t] = v;                                   // St[d][e] = S[e,d]
  } else if (t < 16512) {
    int e = t - 16384;
    float v = bf2f(Q5h[128 * ND + 1920 + e]) + bf2f(Q5l[128 * ND + 1920 + e]);
#pragma unroll
    for (int c = 0; c < CKS; ++c) v += CP[c * PSTR + 128 * 128 + e];
    gv[e] = v;
  }
}

// ---------------------------------------------------------------------------
// Tail (2 wide kernels, fp32-exact S path).
// ---------------------------------------------------------------------------
__global__ __launch_bounds__(256) void tail_T1g(
    const float* __restrict__ St, const float* __restrict__ Wpre,
    const float* __restrict__ bpre, float* __restrict__ T1,
    float* __restrict__ gv) {
  int t = blockIdx.x * 256 + threadIdx.x;
  if (t < 65536) {
    int e = t >> 9, ic = t & 511;
    float s = 0.f;
    for (int d = 0; d < 128; ++d) s += St[d * 128 + e] * Wpre[d * 512 + ic];
    T1[t] = s;
  } else if (t < 65664) {
    int e = t - 65536;
    float s = gv[e];
    for (int d = 0; d < 128; ++d) s += St[d * 128 + e] * bpre[d];
    gv[e] = s;                                   // only this thread touches e
  }
}

__global__ __launch_bounds__(256) void tail_Weff(
    const float* __restrict__ Wpost, const float* __restrict__ T1,
    const float* __restrict__ gv, const float* __restrict__ bpost,
    unsigned short* __restrict__ Whi, unsigned short* __restrict__ Wlo,
    float* __restrict__ beff) {
  int t = blockIdx.x * 256 + threadIdx.x;
  if (t < 262144) {
    int o = t >> 9, ic = t & 511;
    float s = 0.f;
    for (int e = 0; e < 128; ++e) s += Wpost[o * 128 + e] * T1[e * 512 + ic];
    unsigned short h = f2bf(s);
    Whi[t] = h;
    Wlo[t] = f2bf(s - bf2f(h));
  } else if (t < 262656) {
    int o = t - 262144;
    float s = bpost[o];
    for (int e = 0; e < 128; ++e) s += Wpost[o * 128 + e] * gv[e];
    beff[o] = s;
  }
}

// ---------------------------------------------------------------------------
// out[4096,512] = inp @ Weff^T + beff. M=4096,N=512,K=512, split bf16.
// Block tile 64(M) x 128(N): grid (64,4), 4 waves; wave w owns n-cols [32w,32w+32).
// (R10 verified version: simple load->LDS->sync per k-tile.)
// ---------------------------------------------------------------------------
__global__ __launch_bounds__(256) void final_gemm(
    const unsigned short* __restrict__ Ihi, const unsigned short* __restrict__ Ilo,
    const unsigned short* __restrict__ Whi, const unsigned short* __restrict__ Wlo,
    const float* __restrict__ beff, float* __restrict__ out) {
  __shared__ __align__(16) unsigned short Is_hi[64][40], Is_lo[64][40];
  __shared__ __align__(16) unsigned short Ws_hi[128][40], Ws_lo[128][40];
  const int t = threadIdx.x;
  const int mb = blockIdx.x, nb = blockIdx.y;
  const int w = t >> 6, lane = t & 63;
  const int r16 = lane & 15, q = lane >> 4;

  f32x4 acc[4][2];
#pragma unroll
  for (int x = 0; x < 4; ++x)
#pragma unroll
    for (int b = 0; b < 2; ++b) acc[x][b] = (f32x4){0.f, 0.f, 0.f, 0.f};

  for (int kc = 0; kc < 16; ++kc) {
    const int k0 = kc * 32;
#pragma unroll
    for (int rpt = 0; rpt < 6; ++rpt) {
      int slot = t + rpt * 256;
      if (slot < 512) {
        int arr = slot >> 8, s = slot & 255;
        int row = s >> 2, off = (s & 3) * 8;
        const unsigned short* src = arr ? Ilo : Ihi;
        unsigned short* dst = arr ? &Is_lo[row][off] : &Is_hi[row][off];
        *(uint4*)dst = *(const uint4*)(src + (mb * 64 + row) * 512 + k0 + off);
      } else {
        int s = slot - 512;
        int arr = s >> 9, s2 = s & 511;
        int row = s2 >> 2, off = (s2 & 3) * 8;
        const unsigned short* src = arr ? Wlo : Whi;
        unsigned short* dst = arr ? &Ws_lo[row][off] : &Ws_hi[row][off];
        *(uint4*)dst = *(const uint4*)(src + (nb * 128 + row) * 512 + k0 + off);
      }
    }
    __syncthreads();

    bf16x8 bh0 = __builtin_bit_cast(bf16x8, *(const uint4*)&Ws_hi[w * 32 + r16][q * 8]);
    bf16x8 bl0 = __builtin_bit_cast(bf16x8, *(const uint4*)&Ws_lo[w * 32 + r16][q * 8]);
    bf16x8 bh1 = __builtin_bit_cast(bf16x8, *(const uint4*)&Ws_hi[w * 32 + 16 + r16][q * 8]);
    bf16x8 bl1 = __builtin_bit_cast(bf16x8, *(const uint4*)&Ws_lo[w * 32 + 16 + r16][q * 8]);
#pragma unroll
    for (int mt = 0; mt < 4; ++mt) {
      bf16x8 ah = __builtin_bit_cast(bf16x8, *(const uint4*)&Is_hi[mt * 16 + r16][q * 8]);
      bf16x8 al = __builtin_bit_cast(bf16x8, *(const uint4*)&Is_lo[mt * 16 + r16][q * 8]);
      acc[mt][0] = mfma16(ah, bh0, acc[mt][0]);
      acc[mt][0] = mfma16(al, bh0, acc[mt][0]);
      acc[mt][0] = mfma16(ah, bl0, acc[mt][0]);
      acc[mt][1] = mfma16(ah, bh1, acc[mt][1]);
      acc[mt][1] = mfma16(al, bh1, acc[mt][1]);
      acc[mt][1] = mfma16(ah, bl1, acc[mt][1]);
    }
    __syncthreads();
  }

#pragma unroll
  for (int mt = 0; mt < 4; ++mt)
#pragma unroll
    for (int nt = 0; nt < 2; ++nt) {
      int n = nb * 128 + w * 32 + nt * 16 + r16;
      float bv = beff[n];
#pragma unroll
      for (int r = 0; r < 4; ++r) {
        int m = mb * 64 + mt * 16 + q * 4 + r;
        out[m * 512 + n] = acc[mt][nt][r] + bv;
      }
    }
}

extern "C" void kernel_launch(void* const* d_in, const int* in_sizes, int n_in,
                              void* d_out, int out_size, void* d_ws, size_t ws_size,
                              hipStream_t stream) {
  const float* inp   = (const float*)d_in[0];
  const float* Wpre  = (const float*)d_in[1];
  const float* bpre  = (const float*)d_in[2];
  const float* W     = (const float*)d_in[3];
  const float* bl    = (const float*)d_in[4];
  const float* life  = (const float*)d_in[5];
  const float* Wpost = (const float*)d_in[6];
  const float* bpost = (const float*)d_in[7];
  float* out = (float*)d_out;

  char* p = (char*)d_ws;
  auto alloc = [&](size_t bytes) {
    char* r = p;
    p += (bytes + 255) & ~(size_t)255;
    return r;
  };
  unsigned short* Ahi  = (unsigned short*)alloc((size_t)ND * ND * 2);
  unsigned short* Alo  = (unsigned short*)alloc((size_t)ND * ND * 2);
  unsigned short* AThi = (unsigned short*)alloc((size_t)ND * ND * 2);
  unsigned short* ATlo = (unsigned short*)alloc((size_t)ND * ND * 2);
  unsigned short* QqAh = (unsigned short*)alloc((size_t)MT * ND * 2);
  unsigned short* QqAl = (unsigned short*)alloc((size_t)MT * ND * 2);
  unsigned short* QqBh = (unsigned short*)alloc((size_t)MT * ND * 2);
  unsigned short* QqBl = (unsigned short*)alloc((size_t)MT * ND * 2);
  unsigned short* QrAh = (unsigned short*)alloc((size_t)MT * ND * 2);
  unsigned short* QrAl = (unsigned short*)alloc((size_t)MT * ND * 2);
  unsigned short* QrBh = (unsigned short*)alloc((size_t)MT * ND * 2);
  unsigned short* QrBl = (unsigned short*)alloc((size_t)MT * ND * 2);
  float* beta = (float*)alloc(ND * 4);
  float* Pq   = (float*)alloc((size_t)KS * MT * ND * 4);
  float* Pr   = (float*)alloc((size_t)KS * MT * ND * 4);
  float* CP   = (float*)alloc((size_t)CKS * MT * 128 * 4);
  float* St   = (float*)alloc(128 * 128 * 4);
  float* gv   = (float*)alloc(128 * 4);
  float* T1   = (float*)alloc(128 * 512 * 4);
  float* beff = (float*)alloc(512 * 4);
  unsigned short* Whi = (unsigned short*)alloc(512 * 512 * 2);
  unsigned short* Wlo = (unsigned short*)alloc(512 * 512 * 2);
  unsigned short* Ihi = (unsigned short*)alloc((size_t)4096 * 512 * 2);
  unsigned short* Ilo = (unsigned short*)alloc((size_t)4096 * 512 * 2);

  build_all<<<1024, 256, 0, stream>>>(W, life, bl, inp, Ahi, Alo, AThi, ATlo,
                                      QqAh, QqAl, QrAh, QrAl, beta, Ihi, Ilo);

  // 4 paired multiplies: both chains advance A^1 -> A^5
  const unsigned short *qqh = QqAh, *qql = QqAl, *qrh = QrAh, *qrl = QrAl;
  unsigned short *oqh = QqBh, *oql = QqBl, *orh = QrBh, *orl = QrBl;
  for (int s = 0; s < 4; ++s) {
    step_pair<<<dim3(KS, 64, 2), 192, 0, stream>>>(
        Ahi, Alo, AThi, ATlo, qqh, qql, qrh, qrl, Pq, Pr);
    reduce_pair<<<576, 256, 0, stream>>>(Pq, Pr, beta, oqh, oql, orh, orl);
    const unsigned short* t1 = qqh; qqh = oqh; oqh = (unsigned short*)t1;
    const unsigned short* t2 = qql; qql = oql; oql = (unsigned short*)t2;
    const unsigned short* t3 = qrh; qrh = orh; orh = (unsigned short*)t3;
    const unsigned short* t4 = qrl; qrl = orl; orl = (unsigned short*)t4;
  }

  contract_S<<<dim3(CKS, 4), 192, 0, stream>>>(qrh, qrl, qqh, qql, CP);
  extract_Sc<<<65, 256, 0, stream>>>(CP, qqh, qql, St, gv);
  tail_T1g<<<257, 256, 0, stream>>>(St, Wpre, bpre, T1, gv);
  tail_Weff<<<1026, 256, 0, stream>>>(Wpost, T1, gv, bpost, Whi, Wlo, beff);
  final_gemm<<<dim3(64, 4), 256, 0, stream>>>(Ihi, Ilo, Whi, Wlo, beff, out);
}

// Round 13
// 247.335 us; speedup vs baseline: 1.3063x; 1.0252x over previous
//
#include <hip/hip_runtime.h>

// ---------------------------------------------------------------------------
// Algebraic collapse: the scan is linear & batch-independent.
//   m_{t+1} = A m_t + beta,  A[(j,e),(i,d)] = gate[i,j]*W[i,j,e,d]
//   out = inp @ Weff^T + beff,  Weff = Wpost * S * Wpre,
//   S = (A^10)[block15, block0],  c = (sum_{k<10} A^k beta)[block15]
// Round 15: step KS 8->4 with BOTH 256-k halves staged up-front (64KB LDS,
// still 2 blocks/CU -- launch_bounds(192,2) capped residency at 2 anyway, so
// KS=8's extra split bought no occupancy, only doubled P traffic). Each step
// block now runs 16 uninterrupted MFMA iters after one barrier; reduce reads
// 4 partials (halved). Everything else = R14 verified (253.6us).
// Dispatches: 14.
// ---------------------------------------------------------------------------

typedef __bf16 bf16x8 __attribute__((ext_vector_type(8)));
typedef float f32x4 __attribute__((ext_vector_type(4)));
typedef __attribute__((address_space(3))) unsigned int lds_u32;
typedef const __attribute__((address_space(1))) unsigned int glb_u32;

__device__ __forceinline__ unsigned short f2bf(float x) {
  unsigned int u = __float_as_uint(x);
  u += 0x7FFFu + ((u >> 16) & 1u);   // round-to-nearest-even
  return (unsigned short)(u >> 16);
}
__device__ __forceinline__ float bf2f(unsigned short s) {
  return __uint_as_float(((unsigned int)s) << 16);
}
__device__ __forceinline__ bf16x8 ldg8(const unsigned short* p) {
  return __builtin_bit_cast(bf16x8, *(const uint4*)p);
}
__device__ __forceinline__ f32x4 mfma16(bf16x8 a, bf16x8 b, f32x4 c) {
  return __builtin_amdgcn_mfma_f32_16x16x32_bf16(a, b, c, 0, 0, 0);
}

#define ND 2048   // num*dim
#define MT 144    // padded iterate rows (129 used: 128 propagator + 1 bias)
#define KS 4      // split-K chunks (512 k each, staged as 2x256 up-front)
#define CKS 16    // contraction split-K chunks (128 k each)

// ---------------------------------------------------------------------------
// Phase 0 (fused): tiled A+AT build (LDS transpose, W read once), Q-chain
// init Q1 (+beta), R-chain init R1, split inp. Grid-strided jobs.
// ---------------------------------------------------------------------------
__global__ __launch_bounds__(256) void build_all(
    const float* __restrict__ W, const float* __restrict__ life,
    const float* __restrict__ bl, const float* __restrict__ inp,
    unsigned short* __restrict__ Ahi, unsigned short* __restrict__ Alo,
    unsigned short* __restrict__ AThi, unsigned short* __restrict__ ATlo,
    unsigned short* __restrict__ Qhi, unsigned short* __restrict__ Qlo,
    unsigned short* __restrict__ Rhi, unsigned short* __restrict__ Rlo,
    float* __restrict__ beta,
    unsigned short* __restrict__ Ihi, unsigned short* __restrict__ Ilo) {
  __shared__ unsigned short Th[32][36], Tl[32][36];
  const int tid = blockIdx.x * 256 + threadIdx.x;
  const int NT = gridDim.x * 256;
  const int t = threadIdx.x;

  // Job A: per 32x32 tile of A: read W, scale+split, write A and AT.
  {
    const int r = t >> 3;              // 0..31 row within tile
    const int c4 = (t & 7) * 4;        // 0,4,...,28
    for (int tt = blockIdx.x; tt < 4096; tt += gridDim.x) {
      int nt = tt & 63, kt = tt >> 6;
      int j = nt >> 2, e0 = (nt & 3) * 32;
      int i = kt >> 2, d0 = (kt & 3) * 32;
      float gval = life[i * 16 + j];
      float gate = gval > 0.f ? gval : 0.f;
      const float* src = W + ((size_t)(i * 16 + j) * 16384 + (e0 + r) * 128 + d0 + c4);
      float4 v = *(const float4*)src;
      float vals[4] = {v.x, v.y, v.z, v.w};
      union { unsigned short u[4]; uint2 d2; } oh, ol;
#pragma unroll
      for (int x = 0; x < 4; ++x) {
        float s = gate * vals[x];
        oh.u[x] = f2bf(s);
        ol.u[x] = f2bf(s - bf2f(oh.u[x]));
      }
      size_t aidx = (size_t)(j * 128 + e0 + r) * ND + i * 128 + d0 + c4;
      *(uint2*)(Ahi + aidx) = oh.d2;
      *(uint2*)(Alo + aidx) = ol.d2;
      __syncthreads();                 // protect prior iteration's LDS reads
#pragma unroll
      for (int x = 0; x < 4; ++x) { Th[r][c4 + x] = oh.u[x]; Tl[r][c4 + x] = ol.u[x]; }
      __syncthreads();
      union { unsigned short u[4]; uint2 d2; } th, tl;
#pragma unroll
      for (int x = 0; x < 4; ++x) { th.u[x] = Th[c4 + x][r]; tl.u[x] = Tl[c4 + x][r]; }
      size_t tidx = (size_t)(i * 128 + d0 + r) * ND + j * 128 + e0 + c4;
      *(uint2*)(AThi + tidx) = th.d2;
      *(uint2*)(ATlo + tidx) = tl.d2;
    }
  }

  // Job B: Q1[c=d][n=(j,e)] = gate[0,j]*W[0,j,e,d]; row 128 = beta; rest 0.
  for (int item = tid; item < MT * ND; item += NT) {
    int m = item >> 11, n = item & 2047;
    int j = n >> 7, e = n & 127;
    unsigned short hh = 0, ll = 0;
    if (m < 128) {
      float gval = life[j];                         // i = 0
      float gate = gval > 0.f ? gval : 0.f;
      float v = gate * W[j * 16384 + e * 128 + m];
      hh = f2bf(v); ll = f2bf(v - bf2f(hh));
    } else if (m == 128) {
      float s = 0.f;
#pragma unroll
      for (int i = 0; i < 16; ++i) {
        float gval = life[i * 16 + j];
        float gate = gval > 0.f ? gval : 0.f;
        s += gate * bl[(i * 16 + j) * 128 + e];
      }
      beta[n] = s;
      hh = f2bf(s); ll = f2bf(s - bf2f(hh));
    }
    Qhi[item] = hh;
    Qlo[item] = ll;
  }

  // Job B2: R1[r][n=(i,d)] = A[1920+r][n] = gate[i,15]*W[i,15,r,d]; rows>=128: 0
  for (int item = tid; item < MT * ND; item += NT) {
    int m = item >> 11, n = item & 2047;
    int i = n >> 7, d = n & 127;
    unsigned short hh = 0, ll = 0;
    if (m < 128) {
      float gval = life[i * 16 + 15];
      float gate = gval > 0.f ? gval : 0.f;
      float v = gate * W[(size_t)(i * 16 + 15) * 16384 + m * 128 + d];
      hh = f2bf(v); ll = f2bf(v - bf2f(hh));
    }
    Rhi[item] = hh;
    Rlo[item] = ll;
  }

  // Job C: split inp -> hi/lo bf16, 8 elems/item
  for (int item = tid; item < (4096 * 512) / 8; item += NT) {
    int base = item * 8;
    float4 x = *(const float4*)(inp + base), y = *(const float4*)(inp + base + 4);
    float vals[8] = {x.x, x.y, x.z, x.w, y.x, y.y, y.z, y.w};
    union { unsigned short u[8]; uint4 v; } ph, pl;
#pragma unroll
    for (int q = 0; q < 8; ++q) {
      unsigned short h = f2bf(vals[q]);
      ph.u[q] = h;
      pl.u[q] = f2bf(vals[q] - bf2f(h));
    }
    *(uint4*)(Ihi + base) = ph.v;
    *(uint4*)(Ilo + base) = pl.v;
  }
}

// ---------------------------------------------------------------------------
// Pair step: both chains in one launch. Grid (kc, nb, chain) = (4, 64, 2).
// chain 0: P_q[kc][c][n] = sum_k Qq[c][k]*A[n][k]    (Q-chain)
// chain 1: P_r[kc][c][n] = sum_k Qr[c][k]*AT[n][k]   (R-chain, = R*A)
// Block = 3 waves; wave g owns m-rows [g*48,+48). K-chunk = 512, staged as
// TWO 256-k halves up-front into 64KB LDS (one barrier, then 16 MFMA iters
// uninterrupted). 512 blocks = 2 blocks/CU = 6 waves/CU (same residency as
// KS=8 -- launch_bounds cap -- but half the P traffic, 2x amortization).
// ---------------------------------------------------------------------------
__global__ __launch_bounds__(192, 2) void step_pair(
    const unsigned short* __restrict__ Ahi, const unsigned short* __restrict__ Alo,
    const unsigned short* __restrict__ AThi, const unsigned short* __restrict__ ATlo,
    const unsigned short* __restrict__ Qqhi, const unsigned short* __restrict__ Qqlo,
    const unsigned short* __restrict__ Qrhi, const unsigned short* __restrict__ Qrlo,
    float* __restrict__ Pq, float* __restrict__ Pr) {
  // two halves, each [64][256] bf16: rows 0-31 hi, 32-63 lo. 64KB total.
  __shared__ __align__(16) unsigned short AS[2][64][256];
  const int t = threadIdx.x;
  const int g = t >> 6, lane = t & 63;
  const int r16 = lane & 15, q = lane >> 4;
  const int kc = blockIdx.x;
  const int nb = blockIdx.y;
  const int chain = blockIdx.z;
  const unsigned short* Bh = chain ? AThi : Ahi;
  const unsigned short* Bl = chain ? ATlo : Alo;
  const unsigned short* Qh = chain ? Qrhi : Qqhi;
  const unsigned short* Ql = chain ? Qrlo : Qqlo;
  float* P = chain ? Pr : Pq;
  const int kbase = kc * 512;
  const int n0 = nb * 32;

  // ---- stage BOTH halves: 4096 16B-slots as 64 chunks of 64 (1KB each).
  for (int ch = g; ch < 64; ch += 3) {
    int half = ch >> 5, c2 = ch & 31;
    int s = c2 * 64 + lane;
    int row = s >> 5;                       // 0..63
    int c16 = (s & 31) ^ (row & 7);         // inverse swizzle on source
    const unsigned short* src =
        (row < 32 ? Bh + (size_t)(n0 + row) * ND
                  : Bl + (size_t)(n0 + row - 32) * ND) + kbase + half * 256 + c16 * 8;
    __builtin_amdgcn_global_load_lds((glb_u32*)src,
                                     (lds_u32*)(&AS[0][0][0] + ch * 512), 16, 0, 0);
  }

  const int m0 = g * 48 + r16;
  const unsigned short* pA0h = Qh + (size_t)m0 * ND + kbase + q * 8;
  const unsigned short* pA0l = Ql + (size_t)m0 * ND + kbase + q * 8;

  // Q prefetch issued before the barrier: overlaps the stage drain.
  bf16x8 qa[2][6];
#pragma unroll
  for (int f = 0; f < 3; ++f) {
    qa[0][2 * f]     = ldg8(pA0h + f * 16 * ND);
    qa[0][2 * f + 1] = ldg8(pA0l + f * 16 * ND);
  }
  __syncthreads();   // vmcnt(0) drain covers both stage + prefetch

  const uint4* ASv = (const uint4*)&AS[0][0][0];  // 16B units: [half*2048 + row*32 + col]

  f32x4 acc[3][2];
#pragma unroll
  for (int mt = 0; mt < 3; ++mt)
#pragma unroll
    for (int nt = 0; nt < 2; ++nt) acc[mt][nt] = (f32x4){0.f, 0.f, 0.f, 0.f};

#pragma unroll
  for (int it = 0; it < 16; ++it) {
    const int cur = it & 1, nxt = cur ^ 1;
    if (it < 15) {
      const int ko = (it + 1) * 32;
#pragma unroll
      for (int f = 0; f < 3; ++f) {
        qa[nxt][2 * f]     = ldg8(pA0h + f * 16 * ND + ko);
        qa[nxt][2 * f + 1] = ldg8(pA0l + f * 16 * ND + ko);
      }
    }
    const int hbase = (it >> 3) * 2048;            // which 256-k half
    const int it8 = it & 7;
    const int cx = (it8 * 4 + q) ^ (r16 & 7);      // swizzled 16B col
    bf16x8 b0h = __builtin_bit_cast(bf16x8, ASv[hbase + r16 * 32 + cx]);
    bf16x8 b1h = __builtin_bit_cast(bf16x8, ASv[hbase + (16 + r16) * 32 + cx]);
    bf16x8 b0l = __builtin_bit_cast(bf16x8, ASv[hbase + (32 + r16) * 32 + cx]);
    bf16x8 b1l = __builtin_bit_cast(bf16x8, ASv[hbase + (48 + r16) * 32 + cx]);

    acc[0][0] = mfma16(qa[cur][0], b0h, acc[0][0]);
    acc[0][0] = mfma16(qa[cur][1], b0h, acc[0][0]);
    acc[0][0] = mfma16(qa[cur][0], b0l, acc[0][0]);
    acc[1][0] = mfma16(qa[cur][2], b0h, acc[1][0]);
    acc[1][0] = mfma16(qa[cur][3], b0h, acc[1][0]);
    acc[1][0] = mfma16(qa[cur][2], b0l, acc[1][0]);
    acc[2][0] = mfma16(qa[cur][4], b0h, acc[2][0]);
    acc[2][0] = mfma16(qa[cur][5], b0h, acc[2][0]);
    acc[2][0] = mfma16(qa[cur][4], b0l, acc[2][0]);
    acc[0][1] = mfma16(qa[cur][0], b1h, acc[0][1]);
    acc[0][1] = mfma16(qa[cur][1], b1h, acc[0][1]);
    acc[0][1] = mfma16(qa[cur][0], b1l, acc[0][1]);
    acc[1][1] = mfma16(qa[cur][2], b1h, acc[1][1]);
    acc[1][1] = mfma16(qa[cur][3], b1h, acc[1][1]);
    acc[1][1] = mfma16(qa[cur][2], b1l, acc[1][1]);
    acc[2][1] = mfma16(qa[cur][4], b1h, acc[2][1]);
    acc[2][1] = mfma16(qa[cur][5], b1h, acc[2][1]);
    acc[2][1] = mfma16(qa[cur][4], b1l, acc[2][1]);
  }

  float* Pk = P + kc * (MT * ND);
#pragma unroll
  for (int mt = 0; mt < 3; ++mt)
#pragma unroll
    for (int nt = 0; nt < 2; ++nt) {
      int mbase = g * 48 + mt * 16 + q * 4;
      int n = n0 + nt * 16 + r16;
#pragma unroll
      for (int r = 0; r < 4; ++r)
        Pk[(mbase + r) * ND + n] = acc[mt][nt][r];
    }
}

// Sum KS partials for both chains; beta on row 128 of chain 0 only.
__global__ __launch_bounds__(256) void reduce_pair(
    const float* __restrict__ Pq, const float* __restrict__ Pr,
    const float* __restrict__ beta,
    unsigned short* __restrict__ Oqh, unsigned short* __restrict__ Oql,
    unsigned short* __restrict__ Orh, unsigned short* __restrict__ Orl) {
  int bid = blockIdx.x;                     // 0..575
  int chain = bid >= 288;
  int t = (bid - (chain ? 288 : 0)) * 256 + threadIdx.x;
  const float* P = chain ? Pr : Pq;
  unsigned short* Oh = chain ? Orh : Oqh;
  unsigned short* Ol = chain ? Orl : Oql;
  int m = t >> 9;
  int n = (t & 511) * 4;
  int idx = m * ND + n;
  const int stride = MT * ND;
  float v0 = 0.f, v1 = 0.f, v2 = 0.f, v3 = 0.f;
#pragma unroll
  for (int c = 0; c < KS; ++c) {
    float4 s = *(const float4*)(P + c * stride + idx);
    v0 += s.x; v1 += s.y; v2 += s.z; v3 += s.w;
  }
  if (!chain && m == 128) {
    float4 b4 = *(const float4*)(beta + n);
    v0 += b4.x; v1 += b4.y; v2 += b4.z; v3 += b4.w;
  }
  union { unsigned short u[4]; uint2 d; } h, l;
  float vv[4] = {v0, v1, v2, v3};
#pragma unroll
  for (int i = 0; i < 4; ++i) {
    unsigned short hh = f2bf(vv[i]);
    h.u[i] = hh;
    l.u[i] = f2bf(vv[i] - bf2f(hh));
  }
  *(uint2*)(Oh + idx) = h.d;
  *(uint2*)(Ol + idx) = l.d;
}

// ---------------------------------------------------------------------------
// Contraction: CP[kc][m][n] = sum_{k in chunk} Q5[m][k]*R5[n][k].
// Row 128 of Q5 = u -> row 128 of output = R5·u (the c-vector GEMV).
// Grid (16, 4) = 64 blocks, 128-k chunks, same 3-wave structure, 4 iters.
// ---------------------------------------------------------------------------
__global__ __launch_bounds__(192, 2) void contract_S(
    const unsigned short* __restrict__ R5h, const unsigned short* __restrict__ R5l,
    const unsigned short* __restrict__ Q5h, const unsigned short* __restrict__ Q5l,
    float* __restrict__ CP) {
  __shared__ __align__(16) unsigned short AS[64][128];  // 16KB
  const int t = threadIdx.x;
  const int g = t >> 6, lane = t & 63;
  const int r16 = lane & 15, q = lane >> 4;
  const int kc = blockIdx.x;              // 0..15, 128 k each
  const int nb = blockIdx.y;              // 0..3 (n = e in 0..127)
  const int kbase = kc * 128;
  const int n0 = nb * 32;

  // stage R5-tile: 1024 16B-slots as 16 chunks of 64 (16 slots/row)
  for (int ch = g; ch < 16; ch += 3) {
    int s = ch * 64 + lane;
    int row = s >> 4;                     // 0..63
    int c16 = (s & 15) ^ (row & 7);
    const unsigned short* src =
        (row < 32 ? R5h + (size_t)(n0 + row) * ND
                  : R5l + (size_t)(n0 + row - 32) * ND) + kbase + c16 * 8;
    __builtin_amdgcn_global_load_lds((glb_u32*)src,
                                     (lds_u32*)(&AS[0][0] + ch * 512), 16, 0, 0);
  }

  const int m0 = g * 48 + r16;
  const unsigned short* pA0h = Q5h + (size_t)m0 * ND + kbase + q * 8;
  const unsigned short* pA0l = Q5l + (size_t)m0 * ND + kbase + q * 8;

  bf16x8 qa[2][6];
#pragma unroll
  for (int f = 0; f < 3; ++f) {
    qa[0][2 * f]     = ldg8(pA0h + f * 16 * ND);
    qa[0][2 * f + 1] = ldg8(pA0l + f * 16 * ND);
  }
  __syncthreads();

  const uint4* ASv = (const uint4*)&AS[0][0];   // [row*16 + col]

  f32x4 acc[3][2];
#pragma unroll
  for (int mt = 0; mt < 3; ++mt)
#pragma unroll
    for (int nt = 0; nt < 2; ++nt) acc[mt][nt] = (f32x4){0.f, 0.f, 0.f, 0.f};

#pragma unroll
  for (int it = 0; it < 4; ++it) {
    const int cur = it & 1, nxt = cur ^ 1;
    if (it < 3) {
      const int ko = (it + 1) * 32;
#pragma unroll
      for (int f = 0; f < 3; ++f) {
        qa[nxt][2 * f]     = ldg8(pA0h + f * 16 * ND + ko);
        qa[nxt][2 * f + 1] = ldg8(pA0l + f * 16 * ND + ko);
      }
    }
    const int cx = (it * 4 + q) ^ (r16 & 7);   // 0..15 16B cols
    bf16x8 b0h = __builtin_bit_cast(bf16x8, ASv[r16 * 16 + cx]);
    bf16x8 b1h = __builtin_bit_cast(bf16x8, ASv[(16 + r16) * 16 + cx]);
    bf16x8 b0l = __builtin_bit_cast(bf16x8, ASv[(32 + r16) * 16 + cx]);
    bf16x8 b1l = __builtin_bit_cast(bf16x8, ASv[(48 + r16) * 16 + cx]);

    acc[0][0] = mfma16(qa[cur][0], b0h, acc[0][0]);
    acc[0][0] = mfma16(qa[cur][1], b0h, acc[0][0]);
    acc[0][0] = mfma16(qa[cur][0], b0l, acc[0][0]);
    acc[1][0] = mfma16(qa[cur][2], b0h, acc[1][0]);
    acc[1][0] = mfma16(qa[cur][3], b0h, acc[1][0]);
    acc[1][0] = mfma16(qa[cur][2], b0l, acc[1][0]);
    acc[2][0] = mfma16(qa[cur][4], b0h, acc[2][0]);
    acc[2][0] = mfma16(qa[cur][5], b0h, acc[2][0]);
    acc[2][0] = mfma16(qa[cur][4], b0l, acc[2][0]);
    acc[0][1] = mfma16(qa[cur][0], b1h, acc[0][1]);
    acc[0][1] = mfma16(qa[cur][1], b1h, acc[0][1]);
    acc[0][1] = mfma16(qa[cur][0], b1l, acc[0][1]);
    acc[1][1] = mfma16(qa[cur][2], b1h, acc[1][1]);
    acc[1][1] = mfma16(qa[cur][3], b1h, acc[1][1]);
    acc[1][1] = mfma16(qa[cur][2], b1l, acc[1][1]);
    acc[2][1] = mfma16(qa[cur][4], b1h, acc[2][1]);
    acc[2][1] = mfma16(qa[cur][5], b1h, acc[2][1]);
    acc[2][1] = mfma16(qa[cur][4], b1l, acc[2][1]);
  }

  float* Pk = CP + kc * (MT * 128);
#pragma unroll
  for (int mt = 0; mt < 3; ++mt)
#pragma unroll
    for (int nt = 0; nt < 2; ++nt) {
      int mbase = g * 48 + mt * 16 + q * 4;
      int n = n0 + nt * 16 + r16;
#pragma unroll
      for (int r = 0; r < 4; ++r)
        Pk[(mbase + r) * 128 + n] = acc[mt][nt][r];
    }
}

// Reduce contraction partials: St[d][e] = S[e,d]; gv[e] = u[1920+e] + (R5 u)[e]
__global__ __launch_bounds__(256) void extract_Sc(
    const float* __restrict__ CP,
    const unsigned short* __restrict__ Q5h, const unsigned short* __restrict__ Q5l,
    float* __restrict__ St, float* __restrict__ gv) {
  int t = blockIdx.x * 256 + threadIdx.x;
  const int PSTR = MT * 128;
  if (t < 16384) {
    int d = t >> 7, e = t & 127;
    float v = 0.f;
#pragma unroll
    for (int c = 0; c < CKS; ++c) v += CP[c * PSTR + d * 128 + e];
    St[t] = v;                                   // St[d][e] = S[e,d]
  } else if (t < 16512) {
    int e = t - 16384;
    float v = bf2f(Q5h[128 * ND + 1920 + e]) + bf2f(Q5l[128 * ND + 1920 + e]);
#pragma unroll
    for (int c = 0; c < CKS; ++c) v += CP[c * PSTR + 128 * 128 + e];
    gv[e] = v;
  }
}

// ---------------------------------------------------------------------------
// Tail (2 wide kernels, fp32-exact S path).
// ---------------------------------------------------------------------------
__global__ __launch_bounds__(256) void tail_T1g(
    const float* __restrict__ St, const float* __restrict__ Wpre,
    const float* __restrict__ bpre, float* __restrict__ T1,
    float* __restrict__ gv) {
  int t = blockIdx.x * 256 + threadIdx.x;
  if (t < 65536) {
    int e = t >> 9, ic = t & 511;
    float s = 0.f;
    for (int d = 0; d < 128; ++d) s += St[d * 128 + e] * Wpre[d * 512 + ic];
    T1[t] = s;
  } else if (t < 65664) {
    int e = t - 65536;
    float s = gv[e];
    for (int d = 0; d < 128; ++d) s += St[d * 128 + e] * bpre[d];
    gv[e] = s;                                   // only this thread touches e
  }
}

__global__ __launch_bounds__(256) void tail_Weff(
    const float* __restrict__ Wpost, const float* __restrict__ T1,
    const float* __restrict__ gv, const float* __restrict__ bpost,
    unsigned short* __restrict__ Whi, unsigned short* __restrict__ Wlo,
    float* __restrict__ beff) {
  int t = blockIdx.x * 256 + threadIdx.x;
  if (t < 262144) {
    int o = t >> 9, ic = t & 511;
    float s = 0.f;
    for (int e = 0; e < 128; ++e) s += Wpost[o * 128 + e] * T1[e * 512 + ic];
    unsigned short h = f2bf(s);
    Whi[t] = h;
    Wlo[t] = f2bf(s - bf2f(h));
  } else if (t < 262656) {
    int o = t - 262144;
    float s = bpost[o];
    for (int e = 0; e < 128; ++e) s += Wpost[o * 128 + e] * gv[e];
    beff[o] = s;
  }
}

// ---------------------------------------------------------------------------
// out[4096,512] = inp @ Weff^T + beff. M=4096,N=512,K=512, split bf16.
// Block tile 64(M) x 128(N): grid (64,4), 4 waves; wave w owns n-cols [32w,32w+32).
// (R10 verified version: simple load->LDS->sync per k-tile.)
// ---------------------------------------------------------------------------
__global__ __launch_bounds__(256) void final_gemm(
    const unsigned short* __restrict__ Ihi, const unsigned short* __restrict__ Ilo,
    const unsigned short* __restrict__ Whi, const unsigned short* __restrict__ Wlo,
    const float* __restrict__ beff, float* __restrict__ out) {
  __shared__ __align__(16) unsigned short Is_hi[64][40], Is_lo[64][40];
  __shared__ __align__(16) unsigned short Ws_hi[128][40], Ws_lo[128][40];
  const int t = threadIdx.x;
  const int mb = blockIdx.x, nb = blockIdx.y;
  const int w = t >> 6, lane = t & 63;
  const int r16 = lane & 15, q = lane >> 4;

  f32x4 acc[4][2];
#pragma unroll
  for (int x = 0; x < 4; ++x)
#pragma unroll
    for (int b = 0; b < 2; ++b) acc[x][b] = (f32x4){0.f, 0.f, 0.f, 0.f};

  for (int kc = 0; kc < 16; ++kc) {
    const int k0 = kc * 32;
#pragma unroll
    for (int rpt = 0; rpt < 6; ++rpt) {
      int slot = t + rpt * 256;
      if (slot < 512) {
        int arr = slot >> 8, s = slot & 255;
        int row = s >> 2, off = (s & 3) * 8;
        const unsigned short* src = arr ? Ilo : Ihi;
        unsigned short* dst = arr ? &Is_lo[row][off] : &Is_hi[row][off];
        *(uint4*)dst = *(const uint4*)(src + (mb * 64 + row) * 512 + k0 + off);
      } else {
        int s = slot - 512;
        int arr = s >> 9, s2 = s & 511;
        int row = s2 >> 2, off = (s2 & 3) * 8;
        const unsigned short* src = arr ? Wlo : Whi;
        unsigned short* dst = arr ? &Ws_lo[row][off] : &Ws_hi[row][off];
        *(uint4*)dst = *(const uint4*)(src + (nb * 128 + row) * 512 + k0 + off);
      }
    }
    __syncthreads();

    bf16x8 bh0 = __builtin_bit_cast(bf16x8, *(const uint4*)&Ws_hi[w * 32 + r16][q * 8]);
    bf16x8 bl0 = __builtin_bit_cast(bf16x8, *(const uint4*)&Ws_lo[w * 32 + r16][q * 8]);
    bf16x8 bh1 = __builtin_bit_cast(bf16x8, *(const uint4*)&Ws_hi[w * 32 + 16 + r16][q * 8]);
    bf16x8 bl1 = __builtin_bit_cast(bf16x8, *(const uint4*)&Ws_lo[w * 32 + 16 + r16][q * 8]);
#pragma unroll
    for (int mt = 0; mt < 4; ++mt) {
      bf16x8 ah = __builtin_bit_cast(bf16x8, *(const uint4*)&Is_hi[mt * 16 + r16][q * 8]);
      bf16x8 al = __builtin_bit_cast(bf16x8, *(const uint4*)&Is_lo[mt * 16 + r16][q * 8]);
      acc[mt][0] = mfma16(ah, bh0, acc[mt][0]);
      acc[mt][0] = mfma16(al, bh0, acc[mt][0]);
      acc[mt][0] = mfma16(ah, bl0, acc[mt][0]);
      acc[mt][1] = mfma16(ah, bh1, acc[mt][1]);
      acc[mt][1] = mfma16(al, bh1, acc[mt][1]);
      acc[mt][1] = mfma16(ah, bl1, acc[mt][1]);
    }
    __syncthreads();
  }

#pragma unroll
  for (int mt = 0; mt < 4; ++mt)
#pragma unroll
    for (int nt = 0; nt < 2; ++nt) {
      int n = nb * 128 + w * 32 + nt * 16 + r16;
      float bv = beff[n];
#pragma unroll
      for (int r = 0; r < 4; ++r) {
        int m = mb * 64 + mt * 16 + q * 4 + r;
        out[m * 512 + n] = acc[mt][nt][r] + bv;
      }
    }
}

extern "C" void kernel_launch(void* const* d_in, const int* in_sizes, int n_in,
                              void* d_out, int out_size, void* d_ws, size_t ws_size,
                              hipStream_t stream) {
  const float* inp   = (const float*)d_in[0];
  const float* Wpre  = (const float*)d_in[1];
  const float* bpre  = (const float*)d_in[2];
  const float* W     = (const float*)d_in[3];
  const float* bl    = (const float*)d_in[4];
  const float* life  = (const float*)d_in[5];
  const float* Wpost = (const float*)d_in[6];
  const float* bpost = (const float*)d_in[7];
  float* out = (float*)d_out;

  char* p = (char*)d_ws;
  auto alloc = [&](size_t bytes) {
    char* r = p;
    p += (bytes + 255) & ~(size_t)255;
    return r;
  };
  unsigned short* Ahi  = (unsigned short*)alloc((size_t)ND * ND * 2);
  unsigned short* Alo  = (unsigned short*)alloc((size_t)ND * ND * 2);
  unsigned short* AThi = (unsigned short*)alloc((size_t)ND * ND * 2);
  unsigned short* ATlo = (unsigned short*)alloc((size_t)ND * ND * 2);
  unsigned short* QqAh = (unsigned short*)alloc((size_t)MT * ND * 2);
  unsigned short* QqAl = (unsigned short*)alloc((size_t)MT * ND * 2);
  unsigned short* QqBh = (unsigned short*)alloc((size_t)MT * ND * 2);
  unsigned short* QqBl = (unsigned short*)alloc((size_t)MT * ND * 2);
  unsigned short* QrAh = (unsigned short*)alloc((size_t)MT * ND * 2);
  unsigned short* QrAl = (unsigned short*)alloc((size_t)MT * ND * 2);
  unsigned short* QrBh = (unsigned short*)alloc((size_t)MT * ND * 2);
  unsigned short* QrBl = (unsigned short*)alloc((size_t)MT * ND * 2);
  float* beta = (float*)alloc(ND * 4);
  float* Pq   = (float*)alloc((size_t)KS * MT * ND * 4);
  float* Pr   = (float*)alloc((size_t)KS * MT * ND * 4);
  float* CP   = (float*)alloc((size_t)CKS * MT * 128 * 4);
  float* St   = (float*)alloc(128 * 128 * 4);
  float* gv   = (float*)alloc(128 * 4);
  float* T1   = (float*)alloc(128 * 512 * 4);
  float* beff = (float*)alloc(512 * 4);
  unsigned short* Whi = (unsigned short*)alloc(512 * 512 * 2);
  unsigned short* Wlo = (unsigned short*)alloc(512 * 512 * 2);
  unsigned short* Ihi = (unsigned short*)alloc((size_t)4096 * 512 * 2);
  unsigned short* Ilo = (unsigned short*)alloc((size_t)4096 * 512 * 2);

  build_all<<<1024, 256, 0, stream>>>(W, life, bl, inp, Ahi, Alo, AThi, ATlo,
                                      QqAh, QqAl, QrAh, QrAl, beta, Ihi, Ilo);

  // 4 paired multiplies: both chains advance A^1 -> A^5
  const unsigned short *qqh = QqAh, *qql = QqAl, *qrh = QrAh, *qrl = QrAl;
  unsigned short *oqh = QqBh, *oql = QqBl, *orh = QrBh, *orl = QrBl;
  for (int s = 0; s < 4; ++s) {
    step_pair<<<dim3(KS, 64, 2), 192, 0, stream>>>(
        Ahi, Alo, AThi, ATlo, qqh, qql, qrh, qrl, Pq, Pr);
    reduce_pair<<<576, 256, 0, stream>>>(Pq, Pr, beta, oqh, oql, orh, orl);
    const unsigned short* t1 = qqh; qqh = oqh; oqh = (unsigned short*)t1;
    const unsigned short* t2 = qql; qql = oql; oql = (unsigned short*)t2;
    const unsigned short* t3 = qrh; qrh = orh; orh = (unsigned short*)t3;
    const unsigned short* t4 = qrl; qrl = orl; orl = (unsigned short*)t4;
  }

  contract_S<<<dim3(CKS, 4), 192, 0, stream>>>(qrh, qrl, qqh, qql, CP);
  extract_Sc<<<65, 256, 0, stream>>>(CP, qqh, qql, St, gv);
  tail_T1g<<<257, 256, 0, stream>>>(St, Wpre, bpre, T1, gv);
  tail_Weff<<<1026, 256, 0, stream>>>(Wpost, T1, gv, bpost, Whi, Wlo, beff);
  final_gemm<<<dim3(64, 4), 256, 0, stream>>>(Ihi, Ilo, Whi, Wlo, beff, out);
}